// Round 4
// baseline (361.243 us; speedup 1.0000x reference)
//
#include <hip/hip_runtime.h>
#include <hip/hip_bf16.h>

// Problem constants
#define B_ 2
#define S_ 2048
#define DM_ 1024
#define TD_ 1024
#define H_ 16
#define HD_ 64

using bf16 = __hip_bfloat16;
typedef __attribute__((ext_vector_type(8))) short s8v;   // 8 bf16 = one MFMA A/B frag
typedef __attribute__((ext_vector_type(4))) float f4v;   // MFMA C/D frag

__device__ __forceinline__ f4v mfma_bf16(s8v a, s8v b, f4v c) {
    return __builtin_amdgcn_mfma_f32_16x16x32_bf16(a, b, c, 0, 0, 0);
}

// fp32 -> bf16 bits, round-to-nearest-even (inputs are finite)
__device__ __forceinline__ unsigned short f2bf(float f) {
    union { float f; unsigned int u; } v; v.f = f;
    unsigned int r = v.u + 0x7FFFu + ((v.u >> 16) & 1u);
    return (unsigned short)(r >> 16);
}

// Detect whether float tensors are fp32 or bf16.
// cos_q[0] == 1.0 exactly: fp32 word = 0x3F800000 (low16==0); bf16 pair = 0x3F803F80.
__device__ __forceinline__ bool detect_f32(const unsigned int* __restrict__ cosw) {
    return (cosw[0] & 0xFFFFu) == 0u;
}

// Load scalar float from dual-dtype tensor
__device__ __forceinline__ float ld_f(const void* p, int idx, bool f32) {
    return f32 ? ((const float*)p)[idx]
               : __bfloat162float(((const bf16*)p)[idx]);
}

// Stage 8 consecutive elements (bf16) into LDS from dual-dtype row-major source
__device__ __forceinline__ void stage8(const void* src, size_t off, bf16* dst, bool f32) {
    if (!f32) {
        *reinterpret_cast<int4*>(dst) =
            *reinterpret_cast<const int4*>((const bf16*)src + off);
    } else {
        const float* p = (const float*)src + off;
        float4 x = *reinterpret_cast<const float4*>(p);
        float4 y = *reinterpret_cast<const float4*>(p + 4);
        union { unsigned short u[8]; int4 v; } t;
        t.u[0] = f2bf(x.x); t.u[1] = f2bf(x.y); t.u[2] = f2bf(x.z); t.u[3] = f2bf(x.w);
        t.u[4] = f2bf(y.x); t.u[5] = f2bf(y.y); t.u[6] = f2bf(y.z); t.u[7] = f2bf(y.w);
        *reinterpret_cast<int4*>(dst) = t.v;
    }
}

// ---------------------------------------------------------------------------
// Mask -> lengths. 4-way storage detect (mask[0][0] is always True):
//   int32: w0==1; byte: 0x01010101; bf16 1.0 pair: 0x3F803F80; fp32 1.0: 0x3F800000.
// ---------------------------------------------------------------------------
__global__ __launch_bounds__(256)
void compute_lengths(const void* __restrict__ mask, int* __restrict__ lengths) {
    int b = blockIdx.x;
    unsigned int w0 = ((const unsigned int*)mask)[0];
    int enc;                 // 0=i32, 1=u8, 2=bf16, 3=f32
    if (w0 == 1u) enc = 0;
    else if (w0 == 0x01010101u) enc = 1;
    else if (w0 == 0x3F803F80u) enc = 2;
    else enc = 3;
    int cnt = 0;
    for (int s = threadIdx.x; s < S_; s += 256) {
        int i = b * S_ + s;
        bool v;
        if (enc == 0)      v = ((const int*)mask)[i] != 0;
        else if (enc == 1) v = ((const unsigned char*)mask)[i] != 0;
        else if (enc == 2) v = ((const unsigned short*)mask)[i] != 0;
        else               v = ((const float*)mask)[i] != 0.f;
        cnt += v ? 1 : 0;
    }
    __shared__ int red[256];
    red[threadIdx.x] = cnt;
    __syncthreads();
    for (int off = 128; off > 0; off >>= 1) {
        if (threadIdx.x < off) red[threadIdx.x] += red[threadIdx.x + off];
        __syncthreads();
    }
    if (threadIdx.x == 0) lengths[b] = red[0];
}

// ---------------------------------------------------------------------------
// NT GEMM: C[M][N] = A[M][K] * Bm[N][K]^T  (dual-dtype in AND out, fp32 acc)
// a_dyn/b_dyn/c_dyn: 1 = operand/result uses the detected input dtype, 0 = bf16.
// ---------------------------------------------------------------------------
__global__ __launch_bounds__(256)
void gemm_nt(const void* __restrict__ A, const void* __restrict__ Bm,
             void* __restrict__ C, int M, int N, int K,
             int a_dyn, int b_dyn, int c_dyn, const unsigned int* __restrict__ cosw) {
    __shared__ bf16 lds_a[128 * 56];   // 32 cols padded to 56 (112B rows, 16B-aligned)
    __shared__ bf16 lds_b[128 * 56];

    const bool f32 = detect_f32(cosw);
    const bool af32 = a_dyn && f32, bf32 = b_dyn && f32, cf32 = c_dyn && f32;

    const int t = threadIdx.x;
    const int wave = t >> 6, lane = t & 63;
    const int quad = lane >> 4, l16 = lane & 15;
    const int wm = wave >> 1, wn = wave & 1;
    const int m0 = blockIdx.y * 128, n0 = blockIdx.x * 128;

    f4v acc[4][4];
    #pragma unroll
    for (int i = 0; i < 4; i++)
        #pragma unroll
        for (int j = 0; j < 4; j++)
            acc[i][j] = f4v{0.f, 0.f, 0.f, 0.f};

    for (int k0 = 0; k0 < K; k0 += 32) {
        __syncthreads();
        #pragma unroll
        for (int i = 0; i < 2; i++) {
            int ci = i * 256 + t;          // 0..511 chunk of 8 elems
            int row = ci >> 2, c = ci & 3; // 4 chunks per 32-elem row
            stage8(A,  (size_t)(m0 + row) * K + k0 + c * 8, &lds_a[row * 56 + c * 8], af32);
            stage8(Bm, (size_t)(n0 + row) * K + k0 + c * 8, &lds_b[row * 56 + c * 8], bf32);
        }
        __syncthreads();

        s8v afr[4], bfr[4];
        #pragma unroll
        for (int mb = 0; mb < 4; mb++) {
            int r = wm * 64 + mb * 16 + l16;
            afr[mb] = *reinterpret_cast<const s8v*>(&lds_a[r * 56 + quad * 8]);
        }
        #pragma unroll
        for (int nb = 0; nb < 4; nb++) {
            int r = wn * 64 + nb * 16 + l16;
            bfr[nb] = *reinterpret_cast<const s8v*>(&lds_b[r * 56 + quad * 8]);
        }
        #pragma unroll
        for (int mb = 0; mb < 4; mb++)
            #pragma unroll
            for (int nb = 0; nb < 4; nb++)
                acc[mb][nb] = mfma_bf16(afr[mb], bfr[nb], acc[mb][nb]);
    }

    // C/D layout: col = lane&15, row = quad*4 + reg
    #pragma unroll
    for (int mb = 0; mb < 4; mb++) {
        #pragma unroll
        for (int rr = 0; rr < 4; rr++) {
            int m = m0 + wm * 64 + mb * 16 + quad * 4 + rr;
            #pragma unroll
            for (int nb = 0; nb < 4; nb++) {
                int n = n0 + wn * 64 + nb * 16 + l16;
                float v = acc[mb][nb][rr];
                if (cf32) ((float*)C)[(size_t)m * N + n] = v;
                else      ((bf16*)C)[(size_t)m * N + n] = __float2bfloat16(v);
            }
        }
    }
}

// ---------------------------------------------------------------------------
// RoPE + split qkv [B,S,3*TD] (ws, bf16) -> Q,K,V [B,H,S,HD] bf16. Q scaled 1/8.
// ---------------------------------------------------------------------------
__global__ __launch_bounds__(256)
void rope_split(const bf16* __restrict__ qkv,
                const void* __restrict__ sin_t, const void* __restrict__ cos_t,
                bf16* __restrict__ Qh, bf16* __restrict__ Kh, bf16* __restrict__ Vh) {
    const bool f32 = detect_f32((const unsigned int*)cos_t);
    int idx = blockIdx.x * 256 + threadIdx.x;   // B*S*H*HD = 2^22
    int d = idx & 63;
    int h = (idx >> 6) & 15;
    int s = (idx >> 10) & 2047;
    int b = idx >> 21;
    size_t row = (size_t)(b * S_ + s) * 3072;
    int col  = h * 64 + d;
    int colp = h * 64 + ((d + 32) & 63);
    float sgn = (d < 32) ? -1.f : 1.f;
    float cs = ld_f(cos_t, s * 64 + d, f32);
    float sn = ld_f(sin_t, s * 64 + d, f32);
    float q  = __bfloat162float(qkv[row + col]);
    float qp = __bfloat162float(qkv[row + colp]);
    float k  = __bfloat162float(qkv[row + 1024 + col]);
    float kp = __bfloat162float(qkv[row + 1024 + colp]);
    size_t oidx = ((size_t)((b * H_ + h) * S_ + s)) * 64 + d;
    Qh[oidx] = __float2bfloat16((q * cs + sgn * qp * sn) * 0.125f);  // fold 1/sqrt(HD)
    Kh[oidx] = __float2bfloat16(k * cs + sgn * kp * sn);
    Vh[oidx] = qkv[row + 2048 + col];
}

// ---------------------------------------------------------------------------
// Flash attention, causal + key-prefix (lengths) mask.
// Grid: (S/64, H, B). Block 256 = 4 waves; wave w owns q-rows [qb*64+w*16, +16).
// ---------------------------------------------------------------------------
__global__ __launch_bounds__(256)
void attn_fused(const bf16* __restrict__ Qh, const bf16* __restrict__ Kh,
                const bf16* __restrict__ Vh, const int* __restrict__ lengths,
                bf16* __restrict__ out) {
    __shared__ bf16 lds_k[64 * 72];    // K tile   [key][d],  pad 72
    __shared__ bf16 lds_vt[64 * 72];   // V tile^T [d][key],  pad 72
    __shared__ bf16 lds_p[4 * 16 * 72];// per-wave P tile [qrow][key]

    const int t = threadIdx.x, wave = t >> 6, lane = t & 63;
    const int quad = lane >> 4, l16 = lane & 15;
    const int qb = blockIdx.x, h = blockIdx.y, b = blockIdx.z;
    const int qbase = qb * 64;
    const size_t hb = ((size_t)(b * H_ + h)) * S_ * 64;
    int len_raw = lengths[b];
    const int len_b = len_raw < 1 ? 1 : (len_raw > S_ ? S_ : len_raw);  // NaN-proof clamp

    // Q fragments (A-operand): m = lane&15, k = quad*8+j (+32 for second frag)
    s8v qf[2];
    {
        int qrow = qbase + wave * 16 + l16;
        const bf16* qptr = Qh + hb + (size_t)qrow * 64 + quad * 8;
        qf[0] = *reinterpret_cast<const s8v*>(qptr);
        qf[1] = *reinterpret_cast<const s8v*>(qptr + 32);
    }

    f4v o_acc[4];
    #pragma unroll
    for (int a = 0; a < 4; a++) o_acc[a] = f4v{0.f, 0.f, 0.f, 0.f};
    float m_st[4], l_st[4];
    #pragma unroll
    for (int r = 0; r < 4; r++) { m_st[r] = -__builtin_inff(); l_st[r] = 0.f; }

    const int q_row0 = qbase + wave * 16 + quad * 4;  // + r

    // causal bound AND padding bound (block-uniform)
    const int nkt_causal = qb + 1;
    const int nkt_len = (len_b + 63) >> 6;
    const int nkt = nkt_causal < nkt_len ? nkt_causal : nkt_len;

    for (int kt = 0; kt < nkt; kt++) {
        const int kbase = kt * 64;
        __syncthreads();   // prior iter's LDS reads done before overwrite
        #pragma unroll
        for (int i = 0; i < 2; i++) {
            int id = i * 256 + t;          // 0..511
            int row = id >> 3, c = id & 7; // 8 x 16B chunks per 64-elem row
            int4 kv = *reinterpret_cast<const int4*>(Kh + hb + (size_t)(kbase + row) * 64 + c * 8);
            *reinterpret_cast<int4*>(&lds_k[row * 72 + c * 8]) = kv;
            int4 vv = *reinterpret_cast<const int4*>(Vh + hb + (size_t)(kbase + row) * 64 + c * 8);
            union { int4 v; short s[8]; } u; u.v = vv;
            #pragma unroll
            for (int e = 0; e < 8; e++)
                reinterpret_cast<short*>(lds_vt)[(c * 8 + e) * 72 + row] = u.s[e];
        }
        __syncthreads();

        // S = Q K^T : 4 key-blocks of 16, K-dim 64 = 2 MFMA steps
        f4v s_acc[4];
        #pragma unroll
        for (int a = 0; a < 4; a++) s_acc[a] = f4v{0.f, 0.f, 0.f, 0.f};
        #pragma unroll
        for (int kk = 0; kk < 2; kk++) {
            #pragma unroll
            for (int a = 0; a < 4; a++) {
                s8v kf = *reinterpret_cast<const s8v*>(
                    &lds_k[(a * 16 + l16) * 72 + kk * 32 + quad * 8]);
                s_acc[a] = mfma_bf16(qf[kk], kf, s_acc[a]);
            }
        }

        // mask + online softmax (per C-layout row = quad*4 + r)
        #pragma unroll
        for (int r = 0; r < 4; r++) {
            int qrow = q_row0 + r;
            int kmax = (qrow < len_b - 1) ? qrow : (len_b - 1);  // last valid key (>= 0)
            float v0[4];
            float vmax = -__builtin_inff();
            #pragma unroll
            for (int a = 0; a < 4; a++) {
                int key = kbase + a * 16 + l16;
                float sv = s_acc[a][r];
                sv = (key <= kmax) ? sv : -__builtin_inff();
                v0[a] = sv;
                vmax = fmaxf(vmax, sv);
            }
            vmax = fmaxf(vmax, __shfl_xor(vmax, 1));
            vmax = fmaxf(vmax, __shfl_xor(vmax, 2));
            vmax = fmaxf(vmax, __shfl_xor(vmax, 4));
            vmax = fmaxf(vmax, __shfl_xor(vmax, 8));
            float m_old = m_st[r];
            float m_new = fmaxf(m_old, vmax);       // finite from tile 0 (key 0 valid)
            float alpha = __expf(m_old - m_new);
            float psum = 0.f;
            #pragma unroll
            for (int a = 0; a < 4; a++) {
                float p = __expf(v0[a] - m_new);
                psum += p;
                lds_p[(wave * 16 + quad * 4 + r) * 72 + a * 16 + l16] = __float2bfloat16(p);
            }
            psum += __shfl_xor(psum, 1);
            psum += __shfl_xor(psum, 2);
            psum += __shfl_xor(psum, 4);
            psum += __shfl_xor(psum, 8);
            l_st[r] = l_st[r] * alpha + psum;
            m_st[r] = m_new;
            #pragma unroll
            for (int a = 0; a < 4; a++) o_acc[a][r] *= alpha;
        }

        __syncthreads();   // P LDS write -> A-frag read ordering (uniform barrier)

        // O += P V : P as A-operand, V^T rows give contiguous B-frags
        #pragma unroll
        for (int kk = 0; kk < 2; kk++) {
            s8v pf = *reinterpret_cast<const s8v*>(
                &lds_p[(wave * 16 + l16) * 72 + kk * 32 + quad * 8]);
            #pragma unroll
            for (int a = 0; a < 4; a++) {
                s8v vf = *reinterpret_cast<const s8v*>(
                    &lds_vt[(a * 16 + l16) * 72 + kk * 32 + quad * 8]);
                o_acc[a] = mfma_bf16(pf, vf, o_acc[a]);
            }
        }
    }

    // epilogue: out[b, q, h*64 + d] bf16 (internal ws buffer)
    #pragma unroll
    for (int r = 0; r < 4; r++) {
        float inv_l = 1.f / l_st[r];
        int qrow = q_row0 + r;
        size_t orow = ((size_t)(b * S_ + qrow)) * TD_ + h * 64;
        #pragma unroll
        for (int a = 0; a < 4; a++)
            out[orow + a * 16 + l16] = __float2bfloat16(o_acc[a][r] * inv_l);
    }
}

// ---------------------------------------------------------------------------
extern "C" void kernel_launch(void* const* d_in, const int* in_sizes, int n_in,
                              void* d_out, int out_size, void* d_ws, size_t ws_size,
                              hipStream_t stream) {
    const void* query = d_in[0];   // [B,S,DM]  bf16 or fp32 (auto-detected)
    const void* W_in  = d_in[1];   // [3TD,DM]
    const void* W_out = d_in[2];   // [DM,TD]
    const void* sin_q = d_in[3];   // [S,HD]
    const void* cos_q = d_in[4];   // [S,HD]   (cos_q[0] == 1.0 -> dtype probe)
    const void* mask  = d_in[5];   // [B,S] bool, storage auto-detected
    const unsigned int* cosw = (const unsigned int*)cos_q;

    bf16* qkv = (bf16*)d_ws;                             // 4096*3072
    bf16* Qh  = qkv + (size_t)4096 * 3072;               // B*H*S*HD
    bf16* Kh  = Qh + (size_t)B_ * H_ * S_ * HD_;
    bf16* Vh  = Kh + (size_t)B_ * H_ * S_ * HD_;
    bf16* attn = Vh + (size_t)B_ * H_ * S_ * HD_;        // 4096*1024
    int* lengths = (int*)(attn + (size_t)4096 * 1024);   // [B]

    compute_lengths<<<B_, 256, 0, stream>>>(mask, lengths);

    dim3 g1(3072 / 128, 4096 / 128);
    gemm_nt<<<g1, 256, 0, stream>>>(query, W_in, qkv, 4096, 3072, 1024, 1, 1, 0, cosw);

    rope_split<<<(B_ * S_ * H_ * HD_) / 256, 256, 0, stream>>>(qkv, sin_q, cos_q, Qh, Kh, Vh);

    dim3 ga(S_ / 64, H_, B_);
    attn_fused<<<ga, 256, 0, stream>>>(Qh, Kh, Vh, lengths, attn);

    // final GEMM writes d_out in the DETECTED dtype (fp32 if inputs are fp32)
    dim3 g2(1024 / 128, 4096 / 128);
    gemm_nt<<<g2, 256, 0, stream>>>(attn, W_out, d_out, 4096, 1024, 1024, 0, 1, 1, cosw);
}

// Round 5
// 251.187 us; speedup vs baseline: 1.4381x; 1.4381x over previous
//
#include <hip/hip_runtime.h>
#include <hip/hip_bf16.h>

// Problem constants
#define B_ 2
#define S_ 2048
#define DM_ 1024
#define TD_ 1024
#define H_ 16
#define HD_ 64

using bf16 = __hip_bfloat16;
typedef __attribute__((ext_vector_type(8))) short s8v;   // 8 bf16 = one MFMA A/B frag
typedef __attribute__((ext_vector_type(4))) float f4v;   // MFMA C/D frag

__device__ __forceinline__ f4v mfma_bf16(s8v a, s8v b, f4v c) {
    return __builtin_amdgcn_mfma_f32_16x16x32_bf16(a, b, c, 0, 0, 0);
}

// fp32 -> bf16 bits, round-to-nearest-even
__device__ __forceinline__ unsigned short f2bf(float f) {
    union { float f; unsigned int u; } v; v.f = f;
    unsigned int r = v.u + 0x7FFFu + ((v.u >> 16) & 1u);
    return (unsigned short)(r >> 16);
}

// cos_q[0] == 1.0 exactly: fp32 word = 0x3F800000 (low16==0); bf16 pair != 0 low16.
__device__ __forceinline__ bool detect_f32(const unsigned int* __restrict__ cosw) {
    return (cosw[0] & 0xFFFFu) == 0u;
}

__device__ __forceinline__ float ld_f(const void* p, int idx, bool f32) {
    return f32 ? ((const float*)p)[idx]
               : __bfloat162float(((const bf16*)p)[idx]);
}

// ---------------------------------------------------------------------------
// Bulk convert (detected dtype) -> bf16. n multiple of 8.
// ---------------------------------------------------------------------------
__global__ __launch_bounds__(256)
void cvt_bf16(const void* __restrict__ src, bf16* __restrict__ dst, int n,
              const unsigned int* __restrict__ cosw) {
    const bool f32 = detect_f32(cosw);
    int i = (blockIdx.x * 256 + threadIdx.x) * 8;
    if (i >= n) return;
    if (f32) {
        const float* p = (const float*)src + i;
        float4 x = *reinterpret_cast<const float4*>(p);
        float4 y = *reinterpret_cast<const float4*>(p + 4);
        union { unsigned short u[8]; int4 v; } t;
        t.u[0] = f2bf(x.x); t.u[1] = f2bf(x.y); t.u[2] = f2bf(x.z); t.u[3] = f2bf(x.w);
        t.u[4] = f2bf(y.x); t.u[5] = f2bf(y.y); t.u[6] = f2bf(y.z); t.u[7] = f2bf(y.w);
        *reinterpret_cast<int4*>(dst + i) = t.v;
    } else {
        *reinterpret_cast<int4*>(dst + i) =
            *reinterpret_cast<const int4*>((const bf16*)src + i);
    }
}

// ---------------------------------------------------------------------------
// Mask -> lengths (4-way storage detect; mask[0][0] always True).
// ---------------------------------------------------------------------------
__global__ __launch_bounds__(256)
void compute_lengths(const void* __restrict__ mask, int* __restrict__ lengths) {
    int b = blockIdx.x;
    unsigned int w0 = ((const unsigned int*)mask)[0];
    int enc;                 // 0=i32, 1=u8, 2=bf16, 3=f32
    if (w0 == 1u) enc = 0;
    else if (w0 == 0x01010101u) enc = 1;
    else if (w0 == 0x3F803F80u) enc = 2;
    else enc = 3;
    int cnt = 0;
    for (int s = threadIdx.x; s < S_; s += 256) {
        int i = b * S_ + s;
        bool v;
        if (enc == 0)      v = ((const int*)mask)[i] != 0;
        else if (enc == 1) v = ((const unsigned char*)mask)[i] != 0;
        else if (enc == 2) v = ((const unsigned short*)mask)[i] != 0;
        else               v = ((const float*)mask)[i] != 0.f;
        cnt += v ? 1 : 0;
    }
    __shared__ int red[256];
    red[threadIdx.x] = cnt;
    __syncthreads();
    for (int off = 128; off > 0; off >>= 1) {
        if (threadIdx.x < off) red[threadIdx.x] += red[threadIdx.x + off];
        __syncthreads();
    }
    if (threadIdx.x == 0) lengths[b] = red[0];
}

// ---------------------------------------------------------------------------
// NT GEMM: C[M][N] = A[M][K] * Bm[N][K]^T  (bf16 in, fp32 acc).
// c_dyn: 1 -> write detected dtype (fp32 if inputs fp32), 0 -> bf16.
// ---------------------------------------------------------------------------
__global__ __launch_bounds__(256)
void gemm_nt(const bf16* __restrict__ A, const bf16* __restrict__ Bm,
             void* __restrict__ C, int M, int N, int K,
             int c_dyn, const unsigned int* __restrict__ cosw) {
    __shared__ bf16 lds_a[128 * 56];   // 32 cols padded to 56 (144B.. 112B rows, 16B-aligned)
    __shared__ bf16 lds_b[128 * 56];

    const bool cf32 = c_dyn && detect_f32(cosw);

    const int t = threadIdx.x;
    const int wave = t >> 6, lane = t & 63;
    const int quad = lane >> 4, l16 = lane & 15;
    const int wm = wave >> 1, wn = wave & 1;
    const int m0 = blockIdx.y * 128, n0 = blockIdx.x * 128;

    f4v acc[4][4];
    #pragma unroll
    for (int i = 0; i < 4; i++)
        #pragma unroll
        for (int j = 0; j < 4; j++)
            acc[i][j] = f4v{0.f, 0.f, 0.f, 0.f};

    for (int k0 = 0; k0 < K; k0 += 32) {
        __syncthreads();
        #pragma unroll
        for (int i = 0; i < 2; i++) {
            int ci = i * 256 + t;          // 0..511 chunk of 8 elems
            int row = ci >> 2, c = ci & 3; // 4 chunks per 32-elem row
            *reinterpret_cast<int4*>(&lds_a[row * 56 + c * 8]) =
                *reinterpret_cast<const int4*>(A + (size_t)(m0 + row) * K + k0 + c * 8);
            *reinterpret_cast<int4*>(&lds_b[row * 56 + c * 8]) =
                *reinterpret_cast<const int4*>(Bm + (size_t)(n0 + row) * K + k0 + c * 8);
        }
        __syncthreads();

        s8v afr[4], bfr[4];
        #pragma unroll
        for (int mb = 0; mb < 4; mb++) {
            int r = wm * 64 + mb * 16 + l16;
            afr[mb] = *reinterpret_cast<const s8v*>(&lds_a[r * 56 + quad * 8]);
        }
        #pragma unroll
        for (int nb = 0; nb < 4; nb++) {
            int r = wn * 64 + nb * 16 + l16;
            bfr[nb] = *reinterpret_cast<const s8v*>(&lds_b[r * 56 + quad * 8]);
        }
        #pragma unroll
        for (int mb = 0; mb < 4; mb++)
            #pragma unroll
            for (int nb = 0; nb < 4; nb++)
                acc[mb][nb] = mfma_bf16(afr[mb], bfr[nb], acc[mb][nb]);
    }

    // C/D layout: col = lane&15, row = quad*4 + reg
    #pragma unroll
    for (int mb = 0; mb < 4; mb++) {
        #pragma unroll
        for (int rr = 0; rr < 4; rr++) {
            int m = m0 + wm * 64 + mb * 16 + quad * 4 + rr;
            #pragma unroll
            for (int nb = 0; nb < 4; nb++) {
                int n = n0 + wn * 64 + nb * 16 + l16;
                float v = acc[mb][nb][rr];
                if (cf32) ((float*)C)[(size_t)m * N + n] = v;
                else      ((bf16*)C)[(size_t)m * N + n] = __float2bfloat16(v);
            }
        }
    }
}

// ---------------------------------------------------------------------------
// RoPE Q,K: qkv [B,S,3*TD] bf16 -> Qh,Kh [B,H,S,HD] bf16. Q pre-scaled 1/8.
// ---------------------------------------------------------------------------
__global__ __launch_bounds__(256)
void rope_split(const bf16* __restrict__ qkv,
                const void* __restrict__ sin_t, const void* __restrict__ cos_t,
                bf16* __restrict__ Qh, bf16* __restrict__ Kh) {
    const bool f32 = detect_f32((const unsigned int*)cos_t);
    int idx = blockIdx.x * 256 + threadIdx.x;   // B*S*H*HD = 2^22
    int d = idx & 63;
    int h = (idx >> 6) & 15;
    int s = (idx >> 10) & 2047;
    int b = idx >> 21;
    size_t row = (size_t)(b * S_ + s) * 3072;
    int col  = h * 64 + d;
    int colp = h * 64 + ((d + 32) & 63);
    float sgn = (d < 32) ? -1.f : 1.f;
    float cs = ld_f(cos_t, s * 64 + d, f32);
    float sn = ld_f(sin_t, s * 64 + d, f32);
    float q  = __bfloat162float(qkv[row + col]);
    float qp = __bfloat162float(qkv[row + colp]);
    float k  = __bfloat162float(qkv[row + 1024 + col]);
    float kp = __bfloat162float(qkv[row + 1024 + colp]);
    size_t oidx = ((size_t)((b * H_ + h) * S_ + s)) * 64 + d;
    Qh[oidx] = __float2bfloat16((q * cs + sgn * qp * sn) * 0.125f);  // fold 1/sqrt(HD)
    Kh[oidx] = __float2bfloat16(k * cs + sgn * kp * sn);
}

// ---------------------------------------------------------------------------
// V transpose: qkv V-slice [B,S,(2048 + h*64+d)] -> Vt [B,H,HD,S].
// Grid (S/64, H, B), 256 threads. One 64x64 tile per block via LDS.
// ---------------------------------------------------------------------------
__global__ __launch_bounds__(256)
void v_transpose(const bf16* __restrict__ qkv, bf16* __restrict__ Vt) {
    __shared__ bf16 tile[64 * 72];     // [s][d] pad 72
    const int t = threadIdx.x;
    const int sb = blockIdx.x, h = blockIdx.y, b = blockIdx.z;
    #pragma unroll
    for (int i = 0; i < 2; i++) {
        int id = i * 256 + t;          // 0..511
        int row = id >> 3, c = id & 7; // row = s-offset, c = 8-elem d-chunk
        *reinterpret_cast<int4*>(&tile[row * 72 + c * 8]) =
            *reinterpret_cast<const int4*>(
                qkv + (size_t)(b * S_ + sb * 64 + row) * 3072 + 2048 + h * 64 + c * 8);
    }
    __syncthreads();
    const size_t hbt = ((size_t)(b * H_ + h)) * 64 * S_;
    #pragma unroll
    for (int i = 0; i < 2; i++) {
        int id = i * 256 + t;
        int d = id >> 3, c = id & 7;   // c = 8-elem s-chunk
        union { short s[8]; int4 v; } u;
        #pragma unroll
        for (int e = 0; e < 8; e++)
            u.s[e] = reinterpret_cast<const short*>(tile)[(c * 8 + e) * 72 + d];
        *reinterpret_cast<int4*>(Vt + hbt + (size_t)d * S_ + sb * 64 + c * 8) = u.v;
    }
}

// ---------------------------------------------------------------------------
// Flash attention v2: paired q-tiles (qb = p and 31-p -> uniform 33 tile-iters),
// max-free softmax (scores bounded; exp in fp32 has huge headroom),
// V pre-transposed (no in-kernel transpose, no 8-way bank conflicts).
// Grid (16, H, B), 256 threads = 4 waves; wave w owns q-rows [qb*64+w*16,+16).
// ---------------------------------------------------------------------------
__global__ __launch_bounds__(256)
void attn_fused(const bf16* __restrict__ Qh, const bf16* __restrict__ Kh,
                const bf16* __restrict__ Vt, const int* __restrict__ lengths,
                bf16* __restrict__ out) {
    __shared__ bf16 lds_k[64 * 72];    // K tile   [key][d]
    __shared__ bf16 lds_vt[64 * 72];   // V^T tile [d][key]
    __shared__ bf16 lds_p[4 * 16 * 72];// per-wave P tile [qrow][key]

    const int t = threadIdx.x, wave = t >> 6, lane = t & 63;
    const int quad = lane >> 4, l16 = lane & 15;
    const int h = blockIdx.y, b = blockIdx.z;
    const size_t hb  = ((size_t)(b * H_ + h)) * S_ * 64;  // Qh/Kh base
    const size_t hbt = ((size_t)(b * H_ + h)) * 64 * S_;  // Vt base
    int len_raw = lengths[b];
    const int len_b = len_raw < 1 ? 1 : (len_raw > S_ ? S_ : len_raw);

    #pragma unroll
    for (int pass = 0; pass < 2; pass++) {
        const int qb = pass ? (31 - blockIdx.x) : blockIdx.x;
        const int qbase = qb * 64;

        s8v qf[2];
        {
            int qrow = qbase + wave * 16 + l16;
            const bf16* qptr = Qh + hb + (size_t)qrow * 64 + quad * 8;
            qf[0] = *reinterpret_cast<const s8v*>(qptr);
            qf[1] = *reinterpret_cast<const s8v*>(qptr + 32);
        }

        f4v o_acc[4];
        #pragma unroll
        for (int a = 0; a < 4; a++) o_acc[a] = f4v{0.f, 0.f, 0.f, 0.f};
        float l_sum[4] = {0.f, 0.f, 0.f, 0.f};

        const int q_row0 = qbase + wave * 16 + quad * 4;  // + r
        const int nkt_len = (len_b + 63) >> 6;
        const int nkt = (qb + 1) < nkt_len ? (qb + 1) : nkt_len;

        for (int kt = 0; kt < nkt; kt++) {
            const int kbase = kt * 64;
            __syncthreads();   // prior PV reads done before restaging
            #pragma unroll
            for (int i = 0; i < 2; i++) {
                int id = i * 256 + t;
                int row = id >> 3, c = id & 7;
                *reinterpret_cast<int4*>(&lds_k[row * 72 + c * 8]) =
                    *reinterpret_cast<const int4*>(Kh + hb + (size_t)(kbase + row) * 64 + c * 8);
                *reinterpret_cast<int4*>(&lds_vt[row * 72 + c * 8]) =
                    *reinterpret_cast<const int4*>(Vt + hbt + (size_t)row * S_ + kbase + c * 8);
            }
            __syncthreads();

            // S = Q K^T
            f4v s_acc[4];
            #pragma unroll
            for (int a = 0; a < 4; a++) s_acc[a] = f4v{0.f, 0.f, 0.f, 0.f};
            #pragma unroll
            for (int kk = 0; kk < 2; kk++) {
                #pragma unroll
                for (int a = 0; a < 4; a++) {
                    s8v kf = *reinterpret_cast<const s8v*>(
                        &lds_k[(a * 16 + l16) * 72 + kk * 32 + quad * 8]);
                    s_acc[a] = mfma_bf16(qf[kk], kf, s_acc[a]);
                }
            }

            // max-free softmax piece: p = exp(s) (masked 0), lane-local sum
            const bool tail = (kt == qb) || (kbase + 64 > len_b);  // block-uniform
            #pragma unroll
            for (int r = 0; r < 4; r++) {
                int qrow = q_row0 + r;
                int kmax = (qrow < len_b - 1) ? qrow : (len_b - 1);
                #pragma unroll
                for (int a = 0; a < 4; a++) {
                    float p;
                    if (tail) {
                        int key = kbase + a * 16 + l16;
                        p = (key <= kmax) ? __expf(s_acc[a][r]) : 0.f;
                    } else {
                        p = __expf(s_acc[a][r]);
                    }
                    l_sum[r] += p;
                    lds_p[(wave * 16 + quad * 4 + r) * 72 + a * 16 + l16] = __float2bfloat16(p);
                }
            }

            __syncthreads();   // P writes visible to whole wave's A-frag reads

            // O += P V
            #pragma unroll
            for (int kk = 0; kk < 2; kk++) {
                s8v pf = *reinterpret_cast<const s8v*>(
                    &lds_p[(wave * 16 + l16) * 72 + kk * 32 + quad * 8]);
                #pragma unroll
                for (int a = 0; a < 4; a++) {
                    s8v vf = *reinterpret_cast<const s8v*>(
                        &lds_vt[(a * 16 + l16) * 72 + kk * 32 + quad * 8]);
                    o_acc[a] = mfma_bf16(pf, vf, o_acc[a]);
                }
            }
        }

        // one reduction per pass (not per tile)
        #pragma unroll
        for (int r = 0; r < 4; r++) {
            float l = l_sum[r];
            l += __shfl_xor(l, 1);
            l += __shfl_xor(l, 2);
            l += __shfl_xor(l, 4);
            l += __shfl_xor(l, 8);
            float inv_l = 1.f / l;
            int qrow = q_row0 + r;
            size_t orow = ((size_t)(b * S_ + qrow)) * TD_ + h * 64;
            #pragma unroll
            for (int a = 0; a < 4; a++)
                out[orow + a * 16 + l16] = __float2bfloat16(o_acc[a][r] * inv_l);
        }
    }
}

// ---------------------------------------------------------------------------
extern "C" void kernel_launch(void* const* d_in, const int* in_sizes, int n_in,
                              void* d_out, int out_size, void* d_ws, size_t ws_size,
                              hipStream_t stream) {
    const void* query = d_in[0];   // [B,S,DM]  fp32 (auto-detected, bf16-safe)
    const void* W_in  = d_in[1];   // [3TD,DM]
    const void* W_out = d_in[2];   // [DM,TD]
    const void* sin_q = d_in[3];   // [S,HD]
    const void* cos_q = d_in[4];   // [S,HD]   dtype probe
    const void* mask  = d_in[5];   // [B,S] bool, storage auto-detected
    const unsigned int* cosw = (const unsigned int*)cos_q;

    const int nQ  = B_ * S_ * DM_;        // 4194304
    const int nWi = 3 * TD_ * DM_;        // 3145728
    const int nWo = DM_ * TD_;            // 1048576

    bf16* qkv  = (bf16*)d_ws;                         // [4096,3072]
    bf16* Qh   = qkv + (size_t)4096 * 3072;
    bf16* Kh   = Qh + (size_t)nQ;
    bf16* qbf  = Kh + (size_t)nQ;                     // query bf16; reused as Vt
    bf16* wibf = qbf + (size_t)nQ;
    bf16* wobf = wibf + (size_t)nWi;
    int* lengths = (int*)(wobf + (size_t)nWo);
    bf16* Vt   = qbf;    // alias: qbf dead after gemm1, Vt written after
    bf16* attn = qkv;    // alias: qkv dead after rope/v_transpose

    compute_lengths<<<B_, 256, 0, stream>>>(mask, lengths);
    cvt_bf16<<<nQ / (256 * 8), 256, 0, stream>>>(query, qbf, nQ, cosw);
    cvt_bf16<<<nWi / (256 * 8), 256, 0, stream>>>(W_in, wibf, nWi, cosw);
    cvt_bf16<<<nWo / (256 * 8), 256, 0, stream>>>(W_out, wobf, nWo, cosw);

    dim3 g1(3072 / 128, 4096 / 128);
    gemm_nt<<<g1, 256, 0, stream>>>(qbf, wibf, qkv, 4096, 3072, 1024, 0, cosw);

    rope_split<<<(B_ * S_ * H_ * HD_) / 256, 256, 0, stream>>>(qkv, sin_q, cos_q, Qh, Kh);
    dim3 gv(S_ / 64, H_, B_);
    v_transpose<<<gv, 256, 0, stream>>>(qkv, Vt);

    dim3 ga(16, H_, B_);
    attn_fused<<<ga, 256, 0, stream>>>(Qh, Kh, Vt, lengths, attn);

    dim3 g2(1024 / 128, 4096 / 128);
    gemm_nt<<<g2, 256, 0, stream>>>(attn, wobf, d_out, 4096, 1024, 1024, 1, cosw);
}

// Round 6
// 228.217 us; speedup vs baseline: 1.5829x; 1.1006x over previous
//
#include <hip/hip_runtime.h>
#include <hip/hip_bf16.h>

// Problem constants
#define B_ 2
#define S_ 2048
#define DM_ 1024
#define TD_ 1024
#define H_ 16
#define HD_ 64

using bf16 = __hip_bfloat16;
typedef __attribute__((ext_vector_type(8))) short s8v;   // 8 bf16 = one MFMA A/B frag
typedef __attribute__((ext_vector_type(4))) float f4v;   // MFMA C/D frag

__device__ __forceinline__ f4v mfma_bf16(s8v a, s8v b, f4v c) {
    return __builtin_amdgcn_mfma_f32_16x16x32_bf16(a, b, c, 0, 0, 0);
}

// fp32 -> bf16 bits, round-to-nearest-even
__device__ __forceinline__ unsigned short f2bf(float f) {
    union { float f; unsigned int u; } v; v.f = f;
    unsigned int r = v.u + 0x7FFFu + ((v.u >> 16) & 1u);
    return (unsigned short)(r >> 16);
}

// cos_q[0] == 1.0 exactly: fp32 word = 0x3F800000 (low16==0); bf16 pair != 0 low16.
__device__ __forceinline__ bool detect_f32(const unsigned int* __restrict__ cosw) {
    return (cosw[0] & 0xFFFFu) == 0u;
}

__device__ __forceinline__ float ld_f(const void* p, int idx, bool f32) {
    return f32 ? ((const float*)p)[idx]
               : __bfloat162float(((const bf16*)p)[idx]);
}

// async global -> LDS, 16 B per lane (HW: dst = wave-uniform base + lane*16)
__device__ __forceinline__ void gload_lds16(const bf16* g, void* l) {
    __builtin_amdgcn_global_load_lds(
        (const __attribute__((address_space(1))) unsigned int*)(const void*)g,
        (__attribute__((address_space(3))) unsigned int*)l,
        16, 0, 0);
}

// ---------------------------------------------------------------------------
// Merged convert: (query|W_in|W_out) detected-dtype -> contiguous bf16 dst.
// ---------------------------------------------------------------------------
#define NQ_  (B_ * S_ * DM_)
#define NWI_ (3 * TD_ * DM_)
#define NWO_ (DM_ * TD_)
__global__ __launch_bounds__(256)
void cvt_all(const void* __restrict__ q, const void* __restrict__ wi,
             const void* __restrict__ wo, bf16* __restrict__ dst,
             const unsigned int* __restrict__ cosw) {
    const bool f32 = detect_f32(cosw);
    int i = (blockIdx.x * 256 + threadIdx.x) * 8;
    const void* src; int off;
    if (i < NQ_)              { src = q;  off = i; }
    else if (i < NQ_ + NWI_)  { src = wi; off = i - NQ_; }
    else                      { src = wo; off = i - NQ_ - NWI_; }
    if (f32) {
        const float* p = (const float*)src + off;
        float4 x = *reinterpret_cast<const float4*>(p);
        float4 y = *reinterpret_cast<const float4*>(p + 4);
        union { unsigned short u[8]; int4 v; } t;
        t.u[0] = f2bf(x.x); t.u[1] = f2bf(x.y); t.u[2] = f2bf(x.z); t.u[3] = f2bf(x.w);
        t.u[4] = f2bf(y.x); t.u[5] = f2bf(y.y); t.u[6] = f2bf(y.z); t.u[7] = f2bf(y.w);
        *reinterpret_cast<int4*>(dst + i) = t.v;
    } else {
        *reinterpret_cast<int4*>(dst + i) =
            *reinterpret_cast<const int4*>((const bf16*)src + off);
    }
}

// ---------------------------------------------------------------------------
// Mask -> lengths (4-way storage detect; mask[0][0] always True).
// ---------------------------------------------------------------------------
__global__ __launch_bounds__(256)
void compute_lengths(const void* __restrict__ mask, int* __restrict__ lengths) {
    int b = blockIdx.x;
    unsigned int w0 = ((const unsigned int*)mask)[0];
    int enc;                 // 0=i32, 1=u8, 2=bf16, 3=f32
    if (w0 == 1u) enc = 0;
    else if (w0 == 0x01010101u) enc = 1;
    else if (w0 == 0x3F803F80u) enc = 2;
    else enc = 3;
    int cnt = 0;
    for (int s = threadIdx.x; s < S_; s += 256) {
        int i = b * S_ + s;
        bool v;
        if (enc == 0)      v = ((const int*)mask)[i] != 0;
        else if (enc == 1) v = ((const unsigned char*)mask)[i] != 0;
        else if (enc == 2) v = ((const unsigned short*)mask)[i] != 0;
        else               v = ((const float*)mask)[i] != 0.f;
        cnt += v ? 1 : 0;
    }
    __shared__ int red[256];
    red[threadIdx.x] = cnt;
    __syncthreads();
    for (int off = 128; off > 0; off >>= 1) {
        if (threadIdx.x < off) red[threadIdx.x] += red[threadIdx.x + off];
        __syncthreads();
    }
    if (threadIdx.x == 0) lengths[b] = red[0];
}

// ---------------------------------------------------------------------------
// NT GEMM (m97-style): C[M][N] = A[M][K]*Bm[N][K]^T. bf16 in, fp32 acc.
// BK=64, global_load_lds width-16 staging, XOR-swizzled unpadded LDS
// (chunk c stored at c^(row&7) -> b128 reads are 2-way-conflict = free).
// c_dyn: 1 -> write detected dtype (fp32 if inputs fp32), 0 -> bf16.
// ---------------------------------------------------------------------------
__global__ __launch_bounds__(256)
void gemm_nt(const bf16* __restrict__ A, const bf16* __restrict__ Bm,
             void* __restrict__ C, int M, int N, int K,
             int c_dyn, const unsigned int* __restrict__ cosw) {
    __shared__ bf16 lds_a[128 * 64];   // 16 KB, [row][chunk^(row&7)]
    __shared__ bf16 lds_b[128 * 64];

    const bool cf32 = c_dyn && detect_f32(cosw);

    const int t = threadIdx.x;
    const int wave = t >> 6, lane = t & 63;
    const int quad = lane >> 4, l16 = lane & 15;
    const int wm = wave >> 1, wn = wave & 1;
    const int m0 = blockIdx.y * 128, n0 = blockIdx.x * 128;
    const int wuni = __builtin_amdgcn_readfirstlane(wave);   // wave-uniform

    f4v acc[4][4];
    #pragma unroll
    for (int i = 0; i < 4; i++)
        #pragma unroll
        for (int j = 0; j < 4; j++)
            acc[i][j] = f4v{0.f, 0.f, 0.f, 0.f};

    for (int k0 = 0; k0 < K; k0 += 64) {
        __syncthreads();                 // prior reads done before restage
        #pragma unroll
        for (int i = 0; i < 4; i++) {
            int ci = i * 256 + t;        // chunk 0..1023 (16B each)
            int row = ci >> 3;
            int csrc = (ci & 7) ^ (row & 7);
            gload_lds16(A + (size_t)(m0 + row) * K + k0 + csrc * 8,
                        (char*)lds_a + i * 4096 + wuni * 1024);
            gload_lds16(Bm + (size_t)(n0 + row) * K + k0 + csrc * 8,
                        (char*)lds_b + i * 4096 + wuni * 1024);
        }
        __syncthreads();                 // drains vmcnt -> staged data visible

        #pragma unroll
        for (int kk = 0; kk < 2; kk++) {
            s8v afr[4], bfr[4];
            #pragma unroll
            for (int mb = 0; mb < 4; mb++) {
                int r = wm * 64 + mb * 16 + l16;
                int ch = (kk * 4 + quad) ^ (l16 & 7);
                afr[mb] = *reinterpret_cast<const s8v*>(&lds_a[r * 64 + ch * 8]);
            }
            #pragma unroll
            for (int nb = 0; nb < 4; nb++) {
                int r = wn * 64 + nb * 16 + l16;
                int ch = (kk * 4 + quad) ^ (l16 & 7);
                bfr[nb] = *reinterpret_cast<const s8v*>(&lds_b[r * 64 + ch * 8]);
            }
            #pragma unroll
            for (int mb = 0; mb < 4; mb++)
                #pragma unroll
                for (int nb = 0; nb < 4; nb++)
                    acc[mb][nb] = mfma_bf16(afr[mb], bfr[nb], acc[mb][nb]);
        }
    }

    // C/D layout: col = lane&15, row = quad*4 + reg
    #pragma unroll
    for (int mb = 0; mb < 4; mb++) {
        #pragma unroll
        for (int rr = 0; rr < 4; rr++) {
            int m = m0 + wm * 64 + mb * 16 + quad * 4 + rr;
            #pragma unroll
            for (int nb = 0; nb < 4; nb++) {
                int n = n0 + wn * 64 + nb * 16 + l16;
                float v = acc[mb][nb][rr];
                if (cf32) ((float*)C)[(size_t)m * N + n] = v;
                else      ((bf16*)C)[(size_t)m * N + n] = __float2bfloat16(v);
            }
        }
    }
}

// ---------------------------------------------------------------------------
// RoPE Q,K. Q -> Qh [B,H,S,64] linear. K -> Kt tiled+swizzled:
// tile (b,h,sb) is 4096 contiguous elems; slot (s&63, c^(s&7)) holds chunk c.
// Q pre-scaled by 1/8 (fold 1/sqrt(HD)).
// ---------------------------------------------------------------------------
__global__ __launch_bounds__(256)
void rope_split(const bf16* __restrict__ qkv,
                const void* __restrict__ sin_t, const void* __restrict__ cos_t,
                bf16* __restrict__ Qh, bf16* __restrict__ Kt) {
    const bool f32 = detect_f32((const unsigned int*)cos_t);
    int idx = blockIdx.x * 256 + threadIdx.x;   // B*S*H*HD = 2^22
    int d = idx & 63;
    int h = (idx >> 6) & 15;
    int s = (idx >> 10) & 2047;
    int b = idx >> 21;
    size_t row = (size_t)(b * S_ + s) * 3072;
    int col  = h * 64 + d;
    int colp = h * 64 + ((d + 32) & 63);
    float sgn = (d < 32) ? -1.f : 1.f;
    float cs = ld_f(cos_t, s * 64 + d, f32);
    float sn = ld_f(sin_t, s * 64 + d, f32);
    float q  = __bfloat162float(qkv[row + col]);
    float qp = __bfloat162float(qkv[row + colp]);
    float k  = __bfloat162float(qkv[row + 1024 + col]);
    float kp = __bfloat162float(qkv[row + 1024 + colp]);
    Qh[((size_t)((b * H_ + h) * S_ + s)) * 64 + d] =
        __float2bfloat16((q * cs + sgn * qp * sn) * 0.125f);
    // swizzled tiled K store
    size_t ktile = ((size_t)(b * H_ + h) * 32 + (s >> 6)) * 4096;
    int dp = ((((d >> 3) ^ (s & 7)) << 3) | (d & 7));
    Kt[ktile + (s & 63) * 64 + dp] = __float2bfloat16(k * cs + sgn * kp * sn);
}

// ---------------------------------------------------------------------------
// V transpose -> Vt tiled+swizzled: tile (b,h,sb) 4096 elems = [d][keychunk^(d&7)].
// ---------------------------------------------------------------------------
__global__ __launch_bounds__(256)
void v_transpose(const bf16* __restrict__ qkv, bf16* __restrict__ Vt) {
    __shared__ bf16 tile[64 * 72];     // [s][d] pad 72
    const int t = threadIdx.x;
    const int sb = blockIdx.x, h = blockIdx.y, b = blockIdx.z;
    #pragma unroll
    for (int i = 0; i < 2; i++) {
        int id = i * 256 + t;          // 0..511
        int row = id >> 3, c = id & 7; // row = s-offset, c = 8-elem d-chunk
        *reinterpret_cast<int4*>(&tile[row * 72 + c * 8]) =
            *reinterpret_cast<const int4*>(
                qkv + (size_t)(b * S_ + sb * 64 + row) * 3072 + 2048 + h * 64 + c * 8);
    }
    __syncthreads();
    const size_t tb = ((size_t)(b * H_ + h) * 32 + sb) * 4096;
    #pragma unroll
    for (int i = 0; i < 2; i++) {
        int id = i * 256 + t;
        int d = id >> 3, kc = id & 7;  // kc = 8-key chunk
        union { short s[8]; int4 v; } u;
        #pragma unroll
        for (int e = 0; e < 8; e++)
            u.s[e] = reinterpret_cast<const short*>(tile)[(kc * 8 + e) * 72 + d];
        *reinterpret_cast<int4*>(Vt + tb + d * 64 + ((kc ^ (d & 7)) * 8)) = u.v;
    }
}

// ---------------------------------------------------------------------------
// Flash attention v3: paired q-tiles (uniform 33 tile-iters), max-free softmax,
// global_load_lds double-buffered K/V staging (1 barrier per tile),
// wave-local lgkmcnt wait for the P LDS round trip.
// Grid (16, H, B), 256 threads = 4 waves; wave w owns q-rows [qb*64+w*16,+16).
// ---------------------------------------------------------------------------
__global__ __launch_bounds__(256)
void attn_fused(const bf16* __restrict__ Qh, const bf16* __restrict__ Kt,
                const bf16* __restrict__ Vt, const int* __restrict__ lengths,
                bf16* __restrict__ out) {
    __shared__ bf16 k_buf[2 * 4096];   // dbuf K tiles  [row(key)][chunk^(key&7)]
    __shared__ bf16 v_buf[2 * 4096];   // dbuf Vt tiles [row(d)][keychunk^(d&7)]
    __shared__ bf16 lds_p[4 * 16 * 72];// per-wave P tile [qrow][key], pad 72

    const int t = threadIdx.x, wave = t >> 6, lane = t & 63;
    const int quad = lane >> 4, l16 = lane & 15;
    const int h = blockIdx.y, b = blockIdx.z;
    const size_t hb = ((size_t)(b * H_ + h)) * S_ * 64;        // Qh base
    const bf16* Ktp = Kt + ((size_t)(b * H_ + h) * 32) * 4096; // tile array base
    const bf16* Vtp = Vt + ((size_t)(b * H_ + h) * 32) * 4096;
    const int wuni = __builtin_amdgcn_readfirstlane(wave);
    int len_raw = lengths[b];
    const int len_b = len_raw < 1 ? 1 : (len_raw > S_ ? S_ : len_raw);

    #pragma unroll
    for (int pass = 0; pass < 2; pass++) {
        const int qb = pass ? (31 - blockIdx.x) : blockIdx.x;
        const int qbase = qb * 64;

        s8v qf[2];
        {
            int qrow = qbase + wave * 16 + l16;
            const bf16* qptr = Qh + hb + (size_t)qrow * 64 + quad * 8;
            qf[0] = *reinterpret_cast<const s8v*>(qptr);
            qf[1] = *reinterpret_cast<const s8v*>(qptr + 32);
        }

        f4v o_acc[4];
        #pragma unroll
        for (int a = 0; a < 4; a++) o_acc[a] = f4v{0.f, 0.f, 0.f, 0.f};
        float l_sum[4] = {0.f, 0.f, 0.f, 0.f};

        const int q_row0 = qbase + wave * 16 + quad * 4;  // + r
        const int nkt_len = (len_b + 63) >> 6;
        const int nkt = (qb + 1) < nkt_len ? (qb + 1) : nkt_len;

        __syncthreads();   // prior pass's LDS reads done before restaging buf0
        // prefetch tile 0 -> buf0
        #pragma unroll
        for (int i = 0; i < 2; i++) {
            int ci = i * 256 + t;
            gload_lds16(Ktp + ci * 8, (char*)k_buf + i * 4096 + wuni * 1024);
            gload_lds16(Vtp + ci * 8, (char*)v_buf + i * 4096 + wuni * 1024);
        }

        for (int kt = 0; kt < nkt; kt++) {
            const int kbase = kt * 64;
            const int cur = kt & 1;
            __syncthreads();   // drains vmcnt (tile kt staged) + cross-wave sync

            if (kt + 1 < nkt) {   // prefetch kt+1 -> other buffer
                const bf16* kst = Ktp + (size_t)(kt + 1) * 4096;
                const bf16* vst = Vtp + (size_t)(kt + 1) * 4096;
                int bo = (cur ^ 1) * 8192;
                #pragma unroll
                for (int i = 0; i < 2; i++) {
                    int ci = i * 256 + t;
                    gload_lds16(kst + ci * 8, (char*)k_buf + bo + i * 4096 + wuni * 1024);
                    gload_lds16(vst + ci * 8, (char*)v_buf + bo + i * 4096 + wuni * 1024);
                }
            }

            const bf16* kb = k_buf + cur * 4096;
            const bf16* vb = v_buf + cur * 4096;

            // S = Q K^T (swizzled chunk reads)
            f4v s_acc[4];
            #pragma unroll
            for (int a = 0; a < 4; a++) s_acc[a] = f4v{0.f, 0.f, 0.f, 0.f};
            #pragma unroll
            for (int kk = 0; kk < 2; kk++) {
                #pragma unroll
                for (int a = 0; a < 4; a++) {
                    int ch = (kk * 4 + quad) ^ (l16 & 7);
                    s8v kf = *reinterpret_cast<const s8v*>(
                        &kb[(a * 16 + l16) * 64 + ch * 8]);
                    s_acc[a] = mfma_bf16(qf[kk], kf, s_acc[a]);
                }
            }

            // max-free softmax piece: p = exp(s) (masked 0), lane-local sum
            const bool tail = (kt == qb) || (kbase + 64 > len_b);  // block-uniform
            #pragma unroll
            for (int r = 0; r < 4; r++) {
                int qrow = q_row0 + r;
                int kmax = (qrow < len_b - 1) ? qrow : (len_b - 1);
                #pragma unroll
                for (int a = 0; a < 4; a++) {
                    float p;
                    if (tail) {
                        int key = kbase + a * 16 + l16;
                        p = (key <= kmax) ? __expf(s_acc[a][r]) : 0.f;
                    } else {
                        p = __expf(s_acc[a][r]);
                    }
                    l_sum[r] += p;
                    lds_p[(wave * 16 + quad * 4 + r) * 72 + a * 16 + l16] = __float2bfloat16(p);
                }
            }

            // wave-local: P writes -> P reads (lds_p region is per-wave)
            asm volatile("s_waitcnt lgkmcnt(0)" ::: "memory");

            // O += P V
            #pragma unroll
            for (int kk = 0; kk < 2; kk++) {
                s8v pf = *reinterpret_cast<const s8v*>(
                    &lds_p[(wave * 16 + l16) * 72 + kk * 32 + quad * 8]);
                #pragma unroll
                for (int a = 0; a < 4; a++) {
                    int ch = (kk * 4 + quad) ^ (l16 & 7);
                    s8v vf = *reinterpret_cast<const s8v*>(
                        &vb[(a * 16 + l16) * 64 + ch * 8]);
                    o_acc[a] = mfma_bf16(pf, vf, o_acc[a]);
                }
            }
        }

        // one reduction per pass
        #pragma unroll
        for (int r = 0; r < 4; r++) {
            float l = l_sum[r];
            l += __shfl_xor(l, 1);
            l += __shfl_xor(l, 2);
            l += __shfl_xor(l, 4);
            l += __shfl_xor(l, 8);
            float inv_l = 1.f / l;
            int qrow = q_row0 + r;
            size_t orow = ((size_t)(b * S_ + qrow)) * TD_ + h * 64;
            #pragma unroll
            for (int a = 0; a < 4; a++)
                out[orow + a * 16 + l16] = __float2bfloat16(o_acc[a][r] * inv_l);
        }
    }
}

// ---------------------------------------------------------------------------
extern "C" void kernel_launch(void* const* d_in, const int* in_sizes, int n_in,
                              void* d_out, int out_size, void* d_ws, size_t ws_size,
                              hipStream_t stream) {
    const void* query = d_in[0];   // [B,S,DM]  fp32 (auto-detected, bf16-safe)
    const void* W_in  = d_in[1];   // [3TD,DM]
    const void* W_out = d_in[2];   // [DM,TD]
    const void* sin_q = d_in[3];   // [S,HD]
    const void* cos_q = d_in[4];   // [S,HD]   dtype probe
    const void* mask  = d_in[5];   // [B,S] bool, storage auto-detected
    const unsigned int* cosw = (const unsigned int*)cos_q;

    const size_t nQ  = NQ_;   // 4194304
    const size_t nWi = NWI_;  // 3145728
    const size_t nWo = NWO_;  // 1048576

    bf16* qkv  = (bf16*)d_ws;                         // [4096,3072]; later attn out
    bf16* Qh   = qkv + (size_t)4096 * 3072;
    bf16* Kt   = Qh + nQ;                             // tiled+swizzled K
    bf16* qbf  = Kt + nQ;                             // query bf16; later Vt tiles
    bf16* wibf = qbf + nQ;
    bf16* wobf = wibf + nWi;
    int* lengths = (int*)(wobf + nWo);
    bf16* Vt   = qbf;    // alias: qbf dead after gemm1
    bf16* attn = qkv;    // alias: qkv dead after rope/v_transpose

    compute_lengths<<<B_, 256, 0, stream>>>(mask, lengths);
    cvt_all<<<(int)((nQ + nWi + nWo) / (256 * 8)), 256, 0, stream>>>(
        query, W_in, W_out, qbf, cosw);

    dim3 g1(3072 / 128, 4096 / 128);
    gemm_nt<<<g1, 256, 0, stream>>>(qbf, wibf, qkv, 4096, 3072, 1024, 0, cosw);

    rope_split<<<(B_ * S_ * H_ * HD_) / 256, 256, 0, stream>>>(qkv, sin_q, cos_q, Qh, Kt);
    dim3 gv(S_ / 64, H_, B_);
    v_transpose<<<gv, 256, 0, stream>>>(qkv, Vt);

    dim3 ga(16, H_, B_);
    attn_fused<<<ga, 256, 0, stream>>>(Qh, Kt, Vt, lengths, attn);

    dim3 g2(1024 / 128, 4096 / 128);
    gemm_nt<<<g2, 256, 0, stream>>>(attn, wobf, d_out, 4096, 1024, 1024, 1, cosw);
}

// Round 7
// 216.036 us; speedup vs baseline: 1.6721x; 1.0564x over previous
//
#include <hip/hip_runtime.h>
#include <hip/hip_bf16.h>

// Problem constants
#define B_ 2
#define S_ 2048
#define DM_ 1024
#define TD_ 1024
#define H_ 16
#define HD_ 64

using bf16 = __hip_bfloat16;
typedef __attribute__((ext_vector_type(8))) short s8v;   // 8 bf16 = one MFMA A/B frag
typedef __attribute__((ext_vector_type(4))) float f4v;   // MFMA C/D frag

__device__ __forceinline__ f4v mfma_bf16(s8v a, s8v b, f4v c) {
    return __builtin_amdgcn_mfma_f32_16x16x32_bf16(a, b, c, 0, 0, 0);
}

// fp32 -> bf16 bits, round-to-nearest-even
__device__ __forceinline__ unsigned short f2bf(float f) {
    union { float f; unsigned int u; } v; v.f = f;
    unsigned int r = v.u + 0x7FFFu + ((v.u >> 16) & 1u);
    return (unsigned short)(r >> 16);
}

// pack 4 floats -> 4 bf16 in an int2 (for b64 stores)
__device__ __forceinline__ int2 pack4bf(float a, float b, float c, float d) {
    int2 r;
    r.x = (int)((unsigned)f2bf(a) | ((unsigned)f2bf(b) << 16));
    r.y = (int)((unsigned)f2bf(c) | ((unsigned)f2bf(d) << 16));
    return r;
}

// cos_q[0] == 1.0 exactly: fp32 word = 0x3F800000 (low16==0); bf16 pair != 0 low16.
__device__ __forceinline__ bool detect_f32(const unsigned int* __restrict__ cosw) {
    return (cosw[0] & 0xFFFFu) == 0u;
}

__device__ __forceinline__ float ld_f(const void* p, int idx, bool f32) {
    return f32 ? ((const float*)p)[idx]
               : __bfloat162float(((const bf16*)p)[idx]);
}

// async global -> LDS, 16 B per lane (HW: dst = wave-uniform base + lane*16)
__device__ __forceinline__ void gload_lds16(const bf16* g, void* l) {
    __builtin_amdgcn_global_load_lds(
        (const __attribute__((address_space(1))) unsigned int*)(const void*)g,
        (__attribute__((address_space(3))) unsigned int*)l,
        16, 0, 0);
}

// ---------------------------------------------------------------------------
// Merged convert: (query|W_in|W_out) detected-dtype -> contiguous bf16 dst.
// ---------------------------------------------------------------------------
#define NQ_  (B_ * S_ * DM_)
#define NWI_ (3 * TD_ * DM_)
#define NWO_ (DM_ * TD_)
__global__ __launch_bounds__(256)
void cvt_all(const void* __restrict__ q, const void* __restrict__ wi,
             const void* __restrict__ wo, bf16* __restrict__ dst,
             const unsigned int* __restrict__ cosw) {
    const bool f32 = detect_f32(cosw);
    int i = (blockIdx.x * 256 + threadIdx.x) * 8;
    const void* src; int off;
    if (i < NQ_)              { src = q;  off = i; }
    else if (i < NQ_ + NWI_)  { src = wi; off = i - NQ_; }
    else                      { src = wo; off = i - NQ_ - NWI_; }
    if (f32) {
        const float* p = (const float*)src + off;
        float4 x = *reinterpret_cast<const float4*>(p);
        float4 y = *reinterpret_cast<const float4*>(p + 4);
        union { unsigned short u[8]; int4 v; } t;
        t.u[0] = f2bf(x.x); t.u[1] = f2bf(x.y); t.u[2] = f2bf(x.z); t.u[3] = f2bf(x.w);
        t.u[4] = f2bf(y.x); t.u[5] = f2bf(y.y); t.u[6] = f2bf(y.z); t.u[7] = f2bf(y.w);
        *reinterpret_cast<int4*>(dst + i) = t.v;
    } else {
        *reinterpret_cast<int4*>(dst + i) =
            *reinterpret_cast<const int4*>((const bf16*)src + off);
    }
}

// ---------------------------------------------------------------------------
// Mask -> lengths (4-way storage detect; mask[0][0] always True).
// ---------------------------------------------------------------------------
__global__ __launch_bounds__(256)
void compute_lengths(const void* __restrict__ mask, int* __restrict__ lengths) {
    int b = blockIdx.x;
    unsigned int w0 = ((const unsigned int*)mask)[0];
    int enc;                 // 0=i32, 1=u8, 2=bf16, 3=f32
    if (w0 == 1u) enc = 0;
    else if (w0 == 0x01010101u) enc = 1;
    else if (w0 == 0x3F803F80u) enc = 2;
    else enc = 3;
    int cnt = 0;
    for (int s = threadIdx.x; s < S_; s += 256) {
        int i = b * S_ + s;
        bool v;
        if (enc == 0)      v = ((const int*)mask)[i] != 0;
        else if (enc == 1) v = ((const unsigned char*)mask)[i] != 0;
        else if (enc == 2) v = ((const unsigned short*)mask)[i] != 0;
        else               v = ((const float*)mask)[i] != 0.f;
        cnt += v ? 1 : 0;
    }
    __shared__ int red[256];
    red[threadIdx.x] = cnt;
    __syncthreads();
    for (int off = 128; off > 0; off >>= 1) {
        if (threadIdx.x < off) red[threadIdx.x] += red[threadIdx.x + off];
        __syncthreads();
    }
    if (threadIdx.x == 0) lengths[b] = red[0];
}

// ---------------------------------------------------------------------------
// NT GEMM: C[M][N] = A[M][K]*Bm[N][K]^T. bf16 in, fp32 acc. BK=64,
// global_load_lds width-16, XOR-swizzled LDS. MFMA operands SWAPPED
// (D = Bm_tile * A_tile) so each lane owns 4 consecutive n -> b64/b128 stores.
// c_dyn: 1 -> write detected dtype (fp32 if inputs fp32), 0 -> bf16.
// ---------------------------------------------------------------------------
__global__ __launch_bounds__(256)
void gemm_nt(const bf16* __restrict__ A, const bf16* __restrict__ Bm,
             void* __restrict__ C, int M, int N, int K,
             int c_dyn, const unsigned int* __restrict__ cosw) {
    __shared__ bf16 lds_a[128 * 64];   // 16 KB, [row][chunk^(row&7)]
    __shared__ bf16 lds_b[128 * 64];

    const bool cf32 = c_dyn && detect_f32(cosw);

    const int t = threadIdx.x;
    const int wave = t >> 6, lane = t & 63;
    const int quad = lane >> 4, l16 = lane & 15;
    const int wm = wave >> 1, wn = wave & 1;
    const int m0 = blockIdx.y * 128, n0 = blockIdx.x * 128;
    const int wuni = __builtin_amdgcn_readfirstlane(wave);   // wave-uniform

    f4v acc[4][4];
    #pragma unroll
    for (int i = 0; i < 4; i++)
        #pragma unroll
        for (int j = 0; j < 4; j++)
            acc[i][j] = f4v{0.f, 0.f, 0.f, 0.f};

    for (int k0 = 0; k0 < K; k0 += 64) {
        __syncthreads();                 // prior reads done before restage
        #pragma unroll
        for (int i = 0; i < 4; i++) {
            int ci = i * 256 + t;        // chunk 0..1023 (16B each)
            int row = ci >> 3;
            int csrc = (ci & 7) ^ (row & 7);
            gload_lds16(A + (size_t)(m0 + row) * K + k0 + csrc * 8,
                        (char*)lds_a + i * 4096 + wuni * 1024);
            gload_lds16(Bm + (size_t)(n0 + row) * K + k0 + csrc * 8,
                        (char*)lds_b + i * 4096 + wuni * 1024);
        }
        __syncthreads();                 // drains vmcnt -> staged data visible

        #pragma unroll
        for (int kk = 0; kk < 2; kk++) {
            s8v afr[4], bfr[4];
            #pragma unroll
            for (int mb = 0; mb < 4; mb++) {
                int r = wm * 64 + mb * 16 + l16;
                int ch = (kk * 4 + quad) ^ (l16 & 7);
                afr[mb] = *reinterpret_cast<const s8v*>(&lds_a[r * 64 + ch * 8]);
            }
            #pragma unroll
            for (int nb = 0; nb < 4; nb++) {
                int r = wn * 64 + nb * 16 + l16;
                int ch = (kk * 4 + quad) ^ (l16 & 7);
                bfr[nb] = *reinterpret_cast<const s8v*>(&lds_b[r * 64 + ch * 8]);
            }
            // swapped: D[i=n-in-16][j=m-in-16], lane j=l16, regs i=quad*4+rr
            #pragma unroll
            for (int mb = 0; mb < 4; mb++)
                #pragma unroll
                for (int nb = 0; nb < 4; nb++)
                    acc[mb][nb] = mfma_bf16(bfr[nb], afr[mb], acc[mb][nb]);
        }
    }

    // epilogue: m = m0+wm*64+mb*16+l16 (per lane), n = n0+wn*64+nb*16+quad*4+rr
    #pragma unroll
    for (int mb = 0; mb < 4; mb++) {
        int m = m0 + wm * 64 + mb * 16 + l16;
        #pragma unroll
        for (int nb = 0; nb < 4; nb++) {
            int n = n0 + wn * 64 + nb * 16 + quad * 4;
            f4v v = acc[mb][nb];
            if (cf32) {
                *reinterpret_cast<f4v*>(&((float*)C)[(size_t)m * N + n]) = v;
            } else {
                *reinterpret_cast<int2*>(&((bf16*)C)[(size_t)m * N + n]) =
                    pack4bf(v[0], v[1], v[2], v[3]);
            }
        }
    }
}

// ---------------------------------------------------------------------------
// RoPE Q,K. Q -> Qh [B,H,S,64] linear, pre-scaled by 0.125*log2(e) (softmax
// uses exp2). K -> Kt tiled+swizzled: tile (b,h,sb) 4096 elems,
// slot (s&63, c^(s&7)) holds chunk c.
// ---------------------------------------------------------------------------
__global__ __launch_bounds__(256)
void rope_split(const bf16* __restrict__ qkv,
                const void* __restrict__ sin_t, const void* __restrict__ cos_t,
                bf16* __restrict__ Qh, bf16* __restrict__ Kt) {
    const bool f32 = detect_f32((const unsigned int*)cos_t);
    int idx = blockIdx.x * 256 + threadIdx.x;   // B*S*H*HD = 2^22
    int d = idx & 63;
    int h = (idx >> 6) & 15;
    int s = (idx >> 10) & 2047;
    int b = idx >> 21;
    size_t row = (size_t)(b * S_ + s) * 3072;
    int col  = h * 64 + d;
    int colp = h * 64 + ((d + 32) & 63);
    float sgn = (d < 32) ? -1.f : 1.f;
    float cs = ld_f(cos_t, s * 64 + d, f32);
    float sn = ld_f(sin_t, s * 64 + d, f32);
    float q  = __bfloat162float(qkv[row + col]);
    float qp = __bfloat162float(qkv[row + colp]);
    float k  = __bfloat162float(qkv[row + 1024 + col]);
    float kp = __bfloat162float(qkv[row + 1024 + colp]);
    Qh[((size_t)((b * H_ + h) * S_ + s)) * 64 + d] =
        __float2bfloat16((q * cs + sgn * qp * sn) * 0.180336880f);  // 1/8 * log2e
    size_t ktile = ((size_t)(b * H_ + h) * 32 + (s >> 6)) * 4096;
    int dp = ((((d >> 3) ^ (s & 7)) << 3) | (d & 7));
    Kt[ktile + (s & 63) * 64 + dp] = __float2bfloat16(k * cs + sgn * kp * sn);
}

// ---------------------------------------------------------------------------
// V transpose -> Vt tiled+swizzled: tile (b,h,sb) 4096 elems = [d][keychunk^(d&7)].
// ---------------------------------------------------------------------------
__global__ __launch_bounds__(256)
void v_transpose(const bf16* __restrict__ qkv, bf16* __restrict__ Vt) {
    __shared__ bf16 tile[64 * 72];     // [s][d] pad 72
    const int t = threadIdx.x;
    const int sb = blockIdx.x, h = blockIdx.y, b = blockIdx.z;
    #pragma unroll
    for (int i = 0; i < 2; i++) {
        int id = i * 256 + t;          // 0..511
        int row = id >> 3, c = id & 7;
        *reinterpret_cast<int4*>(&tile[row * 72 + c * 8]) =
            *reinterpret_cast<const int4*>(
                qkv + (size_t)(b * S_ + sb * 64 + row) * 3072 + 2048 + h * 64 + c * 8);
    }
    __syncthreads();
    const size_t tb = ((size_t)(b * H_ + h) * 32 + sb) * 4096;
    #pragma unroll
    for (int i = 0; i < 2; i++) {
        int id = i * 256 + t;
        int d = id >> 3, kc = id & 7;  // kc = 8-key chunk
        union { short s[8]; int4 v; } u;
        #pragma unroll
        for (int e = 0; e < 8; e++)
            u.s[e] = reinterpret_cast<const short*>(tile)[(kc * 8 + e) * 72 + d];
        *reinterpret_cast<int4*>(Vt + tb + d * 64 + ((kc ^ (d & 7)) * 8)) = u.v;
    }
}

// ---------------------------------------------------------------------------
// Flash attention v4: transposed-S (swapped MFMA operands) so each lane owns
// ONE q-row (l16) and 4 consecutive keys/d per reg. exp2 softmax (scale folded
// into Q). P round-trip: 4x ds_write_b64 + 2x ds_read_b128, wave-local wait.
// Grid 1024 linear, XCD-clustered: bid&7 = XCD, each (b,h) entirely on one XCD
// (K/V working set 4 x 512 KB = 2 MB <= 4 MB XCD L2).
// ---------------------------------------------------------------------------
__global__ __launch_bounds__(256)
void attn_fused(const bf16* __restrict__ Qh, const bf16* __restrict__ Kt,
                const bf16* __restrict__ Vt, const int* __restrict__ lengths,
                bf16* __restrict__ out) {
    __shared__ bf16 k_buf[2 * 4096];   // dbuf K tiles  [row(key)][chunk^(key&7)]
    __shared__ bf16 v_buf[2 * 4096];   // dbuf Vt tiles [row(d)][keychunk^(d&7)]
    __shared__ bf16 lds_p[4 * 16 * 72];// per-wave P^T-ready tile [qrow][key]

    const int t = threadIdx.x, wave = t >> 6, lane = t & 63;
    const int quad = lane >> 4, l16 = lane & 15;
    // XCD-clustered decode
    const int bid = blockIdx.x;
    const int slot = bid >> 3;
    const int bh = (bid & 7) * 4 + (slot >> 5);   // 0..31, all qb of a bh on one XCD
    const int qb = slot & 31;
    const int b = bh >> 4, h = bh & 15;

    const size_t hb = (size_t)bh * S_ * 64;          // Qh base
    const bf16* Ktp = Kt + (size_t)bh * 32 * 4096;   // tile array base
    const bf16* Vtp = Vt + (size_t)bh * 32 * 4096;
    const int wuni = __builtin_amdgcn_readfirstlane(wave);
    int len_raw = lengths[b];
    const int len_b = len_raw < 1 ? 1 : (len_raw > S_ ? S_ : len_raw);

    const int qbase = qb * 64;
    const int qrow_g = qbase + wave * 16 + l16;       // this lane's q-row
    const int kmax = (qrow_g < len_b - 1) ? qrow_g : (len_b - 1);

    s8v qf[2];
    {
        const bf16* qptr = Qh + hb + (size_t)qrow_g * 64 + quad * 8;
        qf[0] = *reinterpret_cast<const s8v*>(qptr);
        qf[1] = *reinterpret_cast<const s8v*>(qptr + 32);
    }

    f4v o_acc[4];
    #pragma unroll
    for (int a = 0; a < 4; a++) o_acc[a] = f4v{0.f, 0.f, 0.f, 0.f};
    float l_sum = 0.f;

    const int nkt_len = (len_b + 63) >> 6;
    const int nkt = (qb + 1) < nkt_len ? (qb + 1) : nkt_len;

    // prefetch tile 0 -> buf0
    #pragma unroll
    for (int i = 0; i < 2; i++) {
        int ci = i * 256 + t;
        gload_lds16(Ktp + ci * 8, (char*)k_buf + i * 4096 + wuni * 1024);
        gload_lds16(Vtp + ci * 8, (char*)v_buf + i * 4096 + wuni * 1024);
    }

    for (int kt = 0; kt < nkt; kt++) {
        const int kbase = kt * 64;
        const int cur = kt & 1;
        __syncthreads();   // drains vmcnt (tile kt staged) + cross-wave sync

        if (kt + 1 < nkt) {   // prefetch kt+1 -> other buffer
            const bf16* kst = Ktp + (size_t)(kt + 1) * 4096;
            const bf16* vst = Vtp + (size_t)(kt + 1) * 4096;
            int bo = (cur ^ 1) * 8192;
            #pragma unroll
            for (int i = 0; i < 2; i++) {
                int ci = i * 256 + t;
                gload_lds16(kst + ci * 8, (char*)k_buf + bo + i * 4096 + wuni * 1024);
                gload_lds16(vst + ci * 8, (char*)v_buf + bo + i * 4096 + wuni * 1024);
            }
        }

        const bf16* kb = k_buf + cur * 4096;
        const bf16* vb = v_buf + cur * 4096;

        // S^T = K Q^T : lane holds (key = a*16+quad*4+r, qrow = l16)
        f4v s_acc[4];
        #pragma unroll
        for (int a = 0; a < 4; a++) s_acc[a] = f4v{0.f, 0.f, 0.f, 0.f};
        #pragma unroll
        for (int kk = 0; kk < 2; kk++) {
            #pragma unroll
            for (int a = 0; a < 4; a++) {
                int ch = (kk * 4 + quad) ^ (l16 & 7);
                s8v kf = *reinterpret_cast<const s8v*>(
                    &kb[(a * 16 + l16) * 64 + ch * 8]);
                s_acc[a] = mfma_bf16(kf, qf[kk], s_acc[a]);
            }
        }

        // p = exp2(s) (Q pre-scaled by log2e/8), mask only on tail tiles
        const bool tail = (kt == qb) || (kbase + 64 > len_b);  // block-uniform
        #pragma unroll
        for (int a = 0; a < 4; a++) {
            float p0[4];
            #pragma unroll
            for (int r = 0; r < 4; r++) {
                float e = __builtin_amdgcn_exp2f(s_acc[a][r]);
                if (tail) {
                    int key = kbase + a * 16 + quad * 4 + r;
                    e = (key <= kmax) ? e : 0.f;
                }
                p0[r] = e;
                l_sum += e;
            }
            *reinterpret_cast<int2*>(
                &lds_p[(wave * 16 + l16) * 72 + a * 16 + quad * 4]) =
                pack4bf(p0[0], p0[1], p0[2], p0[3]);
        }

        // wave-local: P writes -> P reads (lds_p region is per-wave)
        asm volatile("s_waitcnt lgkmcnt(0)" ::: "memory");

        // O^T += V^T P^T : lane holds (d = a*16+quad*4+r, qrow = l16)
        #pragma unroll
        for (int kk = 0; kk < 2; kk++) {
            s8v pf = *reinterpret_cast<const s8v*>(
                &lds_p[(wave * 16 + l16) * 72 + kk * 32 + quad * 8]);
            #pragma unroll
            for (int a = 0; a < 4; a++) {
                int ch = (kk * 4 + quad) ^ (l16 & 7);
                s8v vf = *reinterpret_cast<const s8v*>(
                    &vb[(a * 16 + l16) * 64 + ch * 8]);
                o_acc[a] = mfma_bf16(vf, pf, o_acc[a]);
            }
        }
    }

    // reduce l across the 4 quads sharing this q-row, then b64 epilogue
    l_sum += __shfl_xor(l_sum, 16);
    l_sum += __shfl_xor(l_sum, 32);
    float inv_l = 1.f / l_sum;
    size_t orow = ((size_t)(b * S_ + qrow_g)) * TD_ + h * 64;
    #pragma unroll
    for (int a = 0; a < 4; a++) {
        *reinterpret_cast<int2*>(&out[orow + a * 16 + quad * 4]) =
            pack4bf(o_acc[a][0] * inv_l, o_acc[a][1] * inv_l,
                    o_acc[a][2] * inv_l, o_acc[a][3] * inv_l);
    }
}

// ---------------------------------------------------------------------------
extern "C" void kernel_launch(void* const* d_in, const int* in_sizes, int n_in,
                              void* d_out, int out_size, void* d_ws, size_t ws_size,
                              hipStream_t stream) {
    const void* query = d_in[0];   // [B,S,DM]  fp32 (auto-detected, bf16-safe)
    const void* W_in  = d_in[1];   // [3TD,DM]
    const void* W_out = d_in[2];   // [DM,TD]
    const void* sin_q = d_in[3];   // [S,HD]
    const void* cos_q = d_in[4];   // [S,HD]   dtype probe
    const void* mask  = d_in[5];   // [B,S] bool, storage auto-detected
    const unsigned int* cosw = (const unsigned int*)cos_q;

    const size_t nQ  = NQ_;   // 4194304
    const size_t nWi = NWI_;  // 3145728
    const size_t nWo = NWO_;  // 1048576

    bf16* qkv  = (bf16*)d_ws;                         // [4096,3072]; later attn out
    bf16* Qh   = qkv + (size_t)4096 * 3072;
    bf16* Kt   = Qh + nQ;                             // tiled+swizzled K
    bf16* qbf  = Kt + nQ;                             // query bf16; later Vt tiles
    bf16* wibf = qbf + nQ;
    bf16* wobf = wibf + nWi;
    int* lengths = (int*)(wobf + nWo);
    bf16* Vt   = qbf;    // alias: qbf dead after gemm1
    bf16* attn = qkv;    // alias: qkv dead after rope/v_transpose

    compute_lengths<<<B_, 256, 0, stream>>>(mask, lengths);
    cvt_all<<<(int)((nQ + nWi + nWo) / (256 * 8)), 256, 0, stream>>>(
        query, W_in, W_out, qbf, cosw);

    dim3 g1(3072 / 128, 4096 / 128);
    gemm_nt<<<g1, 256, 0, stream>>>(qbf, wibf, qkv, 4096, 3072, 1024, 0, cosw);

    rope_split<<<(B_ * S_ * H_ * HD_) / 256, 256, 0, stream>>>(qkv, sin_q, cos_q, Qh, Kt);
    dim3 gv(S_ / 64, H_, B_);
    v_transpose<<<gv, 256, 0, stream>>>(qkv, Vt);

    attn_fused<<<1024, 256, 0, stream>>>(Qh, Kt, Vt, lengths, attn);

    dim3 g2(1024 / 128, 4096 / 128);
    gemm_nt<<<g2, 256, 0, stream>>>(attn, wobf, d_out, 4096, 1024, 1024, 1, cosw);
}

// Round 8
// 206.764 us; speedup vs baseline: 1.7471x; 1.0448x over previous
//
#include <hip/hip_runtime.h>
#include <hip/hip_bf16.h>

// Problem constants
#define B_ 2
#define S_ 2048
#define DM_ 1024
#define TD_ 1024
#define H_ 16
#define HD_ 64

using bf16 = __hip_bfloat16;
typedef __attribute__((ext_vector_type(8))) short s8v;   // 8 bf16 = one MFMA A/B frag
typedef __attribute__((ext_vector_type(4))) float f4v;   // MFMA C/D frag

__device__ __forceinline__ f4v mfma_bf16(s8v a, s8v b, f4v c) {
    return __builtin_amdgcn_mfma_f32_16x16x32_bf16(a, b, c, 0, 0, 0);
}

// HW packed fp32x2 -> bf16x2 (RNE), single VOP3 instr on CDNA3/4
__device__ __forceinline__ unsigned cvt_pk_bf16(float a, float b) {
    unsigned r;
    asm("v_cvt_pk_bf16_f32 %0, %1, %2" : "=v"(r) : "v"(a), "v"(b));
    return r;
}
__device__ __forceinline__ int2 pack4bf(float a, float b, float c, float d) {
    int2 r;
    r.x = (int)cvt_pk_bf16(a, b);
    r.y = (int)cvt_pk_bf16(c, d);
    return r;
}

// cos_q[0] == 1.0 exactly: fp32 word = 0x3F800000 (low16==0); bf16 pair != 0 low16.
__device__ __forceinline__ bool detect_f32(const unsigned int* __restrict__ cosw) {
    return (cosw[0] & 0xFFFFu) == 0u;
}

__device__ __forceinline__ float ld_f(const void* p, int idx, bool f32) {
    return f32 ? ((const float*)p)[idx]
               : __bfloat162float(((const bf16*)p)[idx]);
}

// async global -> LDS, 16 B per lane (HW: dst = wave-uniform base + lane*16)
__device__ __forceinline__ void gload_lds16(const bf16* g, void* l) {
    __builtin_amdgcn_global_load_lds(
        (const __attribute__((address_space(1))) unsigned int*)(const void*)g,
        (__attribute__((address_space(3))) unsigned int*)l,
        16, 0, 0);
}

// ---------------------------------------------------------------------------
// Merged convert: (query|W_in|W_out) detected-dtype -> contiguous bf16 dst.
// ---------------------------------------------------------------------------
#define NQ_  (B_ * S_ * DM_)
#define NWI_ (3 * TD_ * DM_)
#define NWO_ (DM_ * TD_)
__global__ __launch_bounds__(256)
void cvt_all(const void* __restrict__ q, const void* __restrict__ wi,
             const void* __restrict__ wo, bf16* __restrict__ dst,
             const unsigned int* __restrict__ cosw) {
    const bool f32 = detect_f32(cosw);
    int i = (blockIdx.x * 256 + threadIdx.x) * 8;
    const void* src; int off;
    if (i < NQ_)              { src = q;  off = i; }
    else if (i < NQ_ + NWI_)  { src = wi; off = i - NQ_; }
    else                      { src = wo; off = i - NQ_ - NWI_; }
    if (f32) {
        const float* p = (const float*)src + off;
        float4 x = *reinterpret_cast<const float4*>(p);
        float4 y = *reinterpret_cast<const float4*>(p + 4);
        union { unsigned u[4]; int4 v; } t;
        t.u[0] = cvt_pk_bf16(x.x, x.y);
        t.u[1] = cvt_pk_bf16(x.z, x.w);
        t.u[2] = cvt_pk_bf16(y.x, y.y);
        t.u[3] = cvt_pk_bf16(y.z, y.w);
        *reinterpret_cast<int4*>(dst + i) = t.v;
    } else {
        *reinterpret_cast<int4*>(dst + i) =
            *reinterpret_cast<const int4*>((const bf16*)src + off);
    }
}

// ---------------------------------------------------------------------------
// Mask -> lengths (4-way storage detect; mask[0][0] always True).
// ---------------------------------------------------------------------------
__global__ __launch_bounds__(256)
void compute_lengths(const void* __restrict__ mask, int* __restrict__ lengths) {
    int b = blockIdx.x;
    unsigned int w0 = ((const unsigned int*)mask)[0];
    int enc;                 // 0=i32, 1=u8, 2=bf16, 3=f32
    if (w0 == 1u) enc = 0;
    else if (w0 == 0x01010101u) enc = 1;
    else if (w0 == 0x3F803F80u) enc = 2;
    else enc = 3;
    int cnt = 0;
    for (int s = threadIdx.x; s < S_; s += 256) {
        int i = b * S_ + s;
        bool v;
        if (enc == 0)      v = ((const int*)mask)[i] != 0;
        else if (enc == 1) v = ((const unsigned char*)mask)[i] != 0;
        else if (enc == 2) v = ((const unsigned short*)mask)[i] != 0;
        else               v = ((const float*)mask)[i] != 0.f;
        cnt += v ? 1 : 0;
    }
    __shared__ int red[256];
    red[threadIdx.x] = cnt;
    __syncthreads();
    for (int off = 128; off > 0; off >>= 1) {
        if (threadIdx.x < off) red[threadIdx.x] += red[threadIdx.x + off];
        __syncthreads();
    }
    if (threadIdx.x == 0) lengths[b] = red[0];
}

// ---------------------------------------------------------------------------
// NT GEMM: C[M][N] = A[M][K]*Bm[N][K]^T. bf16 in, fp32 acc. BK=64,
// global_load_lds width-16, XOR-swizzled LDS. MFMA operands SWAPPED
// (D = Bm_tile * A_tile) so each lane owns 4 consecutive n -> b64/b128 stores.
// c_dyn: 1 -> write detected dtype (fp32 if inputs fp32), 0 -> bf16.
// ---------------------------------------------------------------------------
__global__ __launch_bounds__(256)
void gemm_nt(const bf16* __restrict__ A, const bf16* __restrict__ Bm,
             void* __restrict__ C, int M, int N, int K,
             int c_dyn, const unsigned int* __restrict__ cosw) {
    __shared__ bf16 lds_a[128 * 64];   // 16 KB, [row][chunk^(row&7)]
    __shared__ bf16 lds_b[128 * 64];

    const bool cf32 = c_dyn && detect_f32(cosw);

    const int t = threadIdx.x;
    const int wave = t >> 6, lane = t & 63;
    const int quad = lane >> 4, l16 = lane & 15;
    const int wm = wave >> 1, wn = wave & 1;
    const int m0 = blockIdx.y * 128, n0 = blockIdx.x * 128;
    const int wuni = __builtin_amdgcn_readfirstlane(wave);   // wave-uniform

    f4v acc[4][4];
    #pragma unroll
    for (int i = 0; i < 4; i++)
        #pragma unroll
        for (int j = 0; j < 4; j++)
            acc[i][j] = f4v{0.f, 0.f, 0.f, 0.f};

    for (int k0 = 0; k0 < K; k0 += 64) {
        __syncthreads();                 // prior reads done before restage
        #pragma unroll
        for (int i = 0; i < 4; i++) {
            int ci = i * 256 + t;        // chunk 0..1023 (16B each)
            int row = ci >> 3;
            int csrc = (ci & 7) ^ (row & 7);
            gload_lds16(A + (size_t)(m0 + row) * K + k0 + csrc * 8,
                        (char*)lds_a + i * 4096 + wuni * 1024);
            gload_lds16(Bm + (size_t)(n0 + row) * K + k0 + csrc * 8,
                        (char*)lds_b + i * 4096 + wuni * 1024);
        }
        __syncthreads();                 // drains vmcnt -> staged data visible

        #pragma unroll
        for (int kk = 0; kk < 2; kk++) {
            s8v afr[4], bfr[4];
            #pragma unroll
            for (int mb = 0; mb < 4; mb++) {
                int r = wm * 64 + mb * 16 + l16;
                int ch = (kk * 4 + quad) ^ (l16 & 7);
                afr[mb] = *reinterpret_cast<const s8v*>(&lds_a[r * 64 + ch * 8]);
            }
            #pragma unroll
            for (int nb = 0; nb < 4; nb++) {
                int r = wn * 64 + nb * 16 + l16;
                int ch = (kk * 4 + quad) ^ (l16 & 7);
                bfr[nb] = *reinterpret_cast<const s8v*>(&lds_b[r * 64 + ch * 8]);
            }
            // swapped: D[i=n-in-16][j=m-in-16], lane j=l16, regs i=quad*4+rr
            #pragma unroll
            for (int mb = 0; mb < 4; mb++)
                #pragma unroll
                for (int nb = 0; nb < 4; nb++)
                    acc[mb][nb] = mfma_bf16(bfr[nb], afr[mb], acc[mb][nb]);
        }
    }

    // epilogue: m = m0+wm*64+mb*16+l16 (per lane), n = n0+wn*64+nb*16+quad*4+rr
    #pragma unroll
    for (int mb = 0; mb < 4; mb++) {
        int m = m0 + wm * 64 + mb * 16 + l16;
        #pragma unroll
        for (int nb = 0; nb < 4; nb++) {
            int n = n0 + wn * 64 + nb * 16 + quad * 4;
            f4v v = acc[mb][nb];
            if (cf32) {
                *reinterpret_cast<f4v*>(&((float*)C)[(size_t)m * N + n]) = v;
            } else {
                *reinterpret_cast<int2*>(&((bf16*)C)[(size_t)m * N + n]) =
                    pack4bf(v[0], v[1], v[2], v[3]);
            }
        }
    }
}

// ---------------------------------------------------------------------------
// RoPE Q,K. Q -> Qh [B,H,S,64] linear, pre-scaled by 0.125*log2(e) (softmax
// uses exp2). K -> Kt tiled+swizzled: tile (b,h,sb) 4096 elems,
// slot (s&63, c^(s&7)) holds chunk c.
// ---------------------------------------------------------------------------
__global__ __launch_bounds__(256)
void rope_split(const bf16* __restrict__ qkv,
                const void* __restrict__ sin_t, const void* __restrict__ cos_t,
                bf16* __restrict__ Qh, bf16* __restrict__ Kt) {
    const bool f32 = detect_f32((const unsigned int*)cos_t);
    int idx = blockIdx.x * 256 + threadIdx.x;   // B*S*H*HD = 2^22
    int d = idx & 63;
    int h = (idx >> 6) & 15;
    int s = (idx >> 10) & 2047;
    int b = idx >> 21;
    size_t row = (size_t)(b * S_ + s) * 3072;
    int col  = h * 64 + d;
    int colp = h * 64 + ((d + 32) & 63);
    float sgn = (d < 32) ? -1.f : 1.f;
    float cs = ld_f(cos_t, s * 64 + d, f32);
    float sn = ld_f(sin_t, s * 64 + d, f32);
    float q  = __bfloat162float(qkv[row + col]);
    float qp = __bfloat162float(qkv[row + colp]);
    float k  = __bfloat162float(qkv[row + 1024 + col]);
    float kp = __bfloat162float(qkv[row + 1024 + colp]);
    Qh[((size_t)((b * H_ + h) * S_ + s)) * 64 + d] =
        __float2bfloat16((q * cs + sgn * qp * sn) * 0.180336880f);  // 1/8 * log2e
    size_t ktile = ((size_t)(b * H_ + h) * 32 + (s >> 6)) * 4096;
    int dp = ((((d >> 3) ^ (s & 7)) << 3) | (d & 7));
    Kt[ktile + (s & 63) * 64 + dp] = __float2bfloat16(k * cs + sgn * kp * sn);
}

// ---------------------------------------------------------------------------
// V transpose -> Vt tiled+swizzled: tile (b,h,sb) 4096 elems = [d][keychunk^(d&7)].
// ---------------------------------------------------------------------------
__global__ __launch_bounds__(256)
void v_transpose(const bf16* __restrict__ qkv, bf16* __restrict__ Vt) {
    __shared__ bf16 tile[64 * 72];     // [s][d] pad 72
    const int t = threadIdx.x;
    const int sb = blockIdx.x, h = blockIdx.y, b = blockIdx.z;
    #pragma unroll
    for (int i = 0; i < 2; i++) {
        int id = i * 256 + t;          // 0..511
        int row = id >> 3, c = id & 7;
        *reinterpret_cast<int4*>(&tile[row * 72 + c * 8]) =
            *reinterpret_cast<const int4*>(
                qkv + (size_t)(b * S_ + sb * 64 + row) * 3072 + 2048 + h * 64 + c * 8);
    }
    __syncthreads();
    const size_t tb = ((size_t)(b * H_ + h) * 32 + sb) * 4096;
    #pragma unroll
    for (int i = 0; i < 2; i++) {
        int id = i * 256 + t;
        int d = id >> 3, kc = id & 7;  // kc = 8-key chunk
        union { short s[8]; int4 v; } u;
        #pragma unroll
        for (int e = 0; e < 8; e++)
            u.s[e] = reinterpret_cast<const short*>(tile)[(kc * 8 + e) * 72 + d];
        *reinterpret_cast<int4*>(Vt + tb + d * 64 + ((kc ^ (d & 7)) * 8)) = u.v;
    }
}

// ---------------------------------------------------------------------------
// Flash attention v5: transposed-S + depth-2 software pipeline.
// At iter kt: stage V[kt] & K[kt+1]; S-MFMA tile kt; exp/pack/PV tile kt-1
// (the exp VALU chain hides under the S-MFMA shadow; MFMA+VALU co-issue).
// One barrier per iter. Grid 1024 linear, XCD-clustered (bid&7 = XCD).
// ---------------------------------------------------------------------------
__global__ __launch_bounds__(256)
void attn_fused(const bf16* __restrict__ Qh, const bf16* __restrict__ Kt,
                const bf16* __restrict__ Vt, const int* __restrict__ lengths,
                bf16* __restrict__ out) {
    __shared__ bf16 k_buf[2 * 4096];   // K tiles  [row(key)][chunk^(key&7)]
    __shared__ bf16 v_buf[2 * 4096];   // Vt tiles [row(d)][keychunk^(d&7)]
    __shared__ bf16 lds_p[4 * 16 * 72];// per-wave P tile [qrow][key]

    const int t = threadIdx.x, wave = t >> 6, lane = t & 63;
    const int quad = lane >> 4, l16 = lane & 15;
    // XCD-clustered decode
    const int bid = blockIdx.x;
    const int slot = bid >> 3;
    const int bh = (bid & 7) * 4 + (slot >> 5);   // all qb of a bh on one XCD
    const int qb = slot & 31;
    const int b = bh >> 4, h = bh & 15;

    const size_t hb = (size_t)bh * S_ * 64;          // Qh base
    const bf16* Ktp = Kt + (size_t)bh * 32 * 4096;   // tile array base
    const bf16* Vtp = Vt + (size_t)bh * 32 * 4096;
    const int wuni = __builtin_amdgcn_readfirstlane(wave);
    int len_raw = lengths[b];
    const int len_b = len_raw < 1 ? 1 : (len_raw > S_ ? S_ : len_raw);

    const int qbase = qb * 64;
    const int qrow_g = qbase + wave * 16 + l16;       // this lane's q-row
    const int kmax = (qrow_g < len_b - 1) ? qrow_g : (len_b - 1);

    s8v qf[2];
    {
        const bf16* qptr = Qh + hb + (size_t)qrow_g * 64 + quad * 8;
        qf[0] = *reinterpret_cast<const s8v*>(qptr);
        qf[1] = *reinterpret_cast<const s8v*>(qptr + 32);
    }

    f4v o_acc[4];
    #pragma unroll
    for (int a = 0; a < 4; a++) o_acc[a] = f4v{0.f, 0.f, 0.f, 0.f};
    float l_sum = 0.f;

    const int nkt_len = (len_b + 63) >> 6;
    const int nkt = (qb + 1) < nkt_len ? (qb + 1) : nkt_len;

    // exp + P pack + PV for tile pt (s_prev holds S^T[pt])
    f4v s_prev[4];
    auto process_tile = [&](int pt, const bf16* vb) {
        const int pbase = pt * 64;
        const bool tail = (pt == qb) || (pbase + 64 > len_b);  // block-uniform
        #pragma unroll
        for (int a = 0; a < 4; a++) {
            float e0[4];
            #pragma unroll
            for (int r = 0; r < 4; r++) {
                float e = __builtin_amdgcn_exp2f(s_prev[a][r]);
                if (tail) {
                    int key = pbase + a * 16 + quad * 4 + r;
                    e = (key <= kmax) ? e : 0.f;
                }
                e0[r] = e;
                l_sum += e;
            }
            *reinterpret_cast<int2*>(
                &lds_p[(wave * 16 + l16) * 72 + a * 16 + quad * 4]) =
                pack4bf(e0[0], e0[1], e0[2], e0[3]);
        }
        // wave-local: P writes -> P reads (lds_p region is per-wave)
        asm volatile("s_waitcnt lgkmcnt(0)" ::: "memory");
        #pragma unroll
        for (int kk = 0; kk < 2; kk++) {
            s8v pf = *reinterpret_cast<const s8v*>(
                &lds_p[(wave * 16 + l16) * 72 + kk * 32 + quad * 8]);
            #pragma unroll
            for (int a = 0; a < 4; a++) {
                int ch = (kk * 4 + quad) ^ (l16 & 7);
                s8v vf = *reinterpret_cast<const s8v*>(
                    &vb[(a * 16 + l16) * 64 + ch * 8]);
                o_acc[a] = mfma_bf16(vf, pf, o_acc[a]);
            }
        }
    };

    // prologue: stage K[0]
    #pragma unroll
    for (int i = 0; i < 2; i++) {
        int ci = i * 256 + t;
        gload_lds16(Ktp + ci * 8, (char*)k_buf + i * 4096 + wuni * 1024);
    }
    __syncthreads();   // K[0] resident

    for (int kt = 0; kt < nkt; kt++) {
        const int cur = kt & 1;
        // stage V[kt] -> vbuf[cur] (one tile behind K)
        {
            const bf16* vst = Vtp + (size_t)kt * 4096;
            #pragma unroll
            for (int i = 0; i < 2; i++) {
                int ci = i * 256 + t;
                gload_lds16(vst + ci * 8,
                            (char*)v_buf + cur * 8192 + i * 4096 + wuni * 1024);
            }
        }
        // stage K[kt+1] -> kbuf[cur^1]
        if (kt + 1 < nkt) {
            const bf16* kst = Ktp + (size_t)(kt + 1) * 4096;
            #pragma unroll
            for (int i = 0; i < 2; i++) {
                int ci = i * 256 + t;
                gload_lds16(kst + ci * 8,
                            (char*)k_buf + (cur ^ 1) * 8192 + i * 4096 + wuni * 1024);
            }
        }

        // S^T[kt] = K Q^T : lane holds (key = a*16+quad*4+r, qrow = l16)
        const bf16* kb = k_buf + cur * 4096;
        f4v s_acc[4];
        #pragma unroll
        for (int a = 0; a < 4; a++) s_acc[a] = f4v{0.f, 0.f, 0.f, 0.f};
        #pragma unroll
        for (int kk = 0; kk < 2; kk++) {
            #pragma unroll
            for (int a = 0; a < 4; a++) {
                int ch = (kk * 4 + quad) ^ (l16 & 7);
                s8v kf = *reinterpret_cast<const s8v*>(
                    &kb[(a * 16 + l16) * 64 + ch * 8]);
                s_acc[a] = mfma_bf16(kf, qf[kk], s_acc[a]);
            }
        }

        // overlap: previous tile's exp/pack/PV under this tile's S-MFMA
        if (kt > 0) process_tile(kt - 1, v_buf + ((kt - 1) & 1) * 4096);

        #pragma unroll
        for (int a = 0; a < 4; a++) s_prev[a] = s_acc[a];

        __syncthreads();   // V[kt], K[kt+1] staged; LDS reads done before reuse
    }
    // drain: last tile
    process_tile(nkt - 1, v_buf + ((nkt - 1) & 1) * 4096);

    // reduce l across the 4 quads sharing this q-row, then b64 epilogue
    l_sum += __shfl_xor(l_sum, 16);
    l_sum += __shfl_xor(l_sum, 32);
    float inv_l = 1.f / l_sum;
    size_t orow = ((size_t)(b * S_ + qrow_g)) * TD_ + h * 64;
    #pragma unroll
    for (int a = 0; a < 4; a++) {
        *reinterpret_cast<int2*>(&out[orow + a * 16 + quad * 4]) =
            pack4bf(o_acc[a][0] * inv_l, o_acc[a][1] * inv_l,
                    o_acc[a][2] * inv_l, o_acc[a][3] * inv_l);
    }
}

// ---------------------------------------------------------------------------
extern "C" void kernel_launch(void* const* d_in, const int* in_sizes, int n_in,
                              void* d_out, int out_size, void* d_ws, size_t ws_size,
                              hipStream_t stream) {
    const void* query = d_in[0];   // [B,S,DM]  fp32 (auto-detected, bf16-safe)
    const void* W_in  = d_in[1];   // [3TD,DM]
    const void* W_out = d_in[2];   // [DM,TD]
    const void* sin_q = d_in[3];   // [S,HD]
    const void* cos_q = d_in[4];   // [S,HD]   dtype probe
    const void* mask  = d_in[5];   // [B,S] bool, storage auto-detected
    const unsigned int* cosw = (const unsigned int*)cos_q;

    const size_t nQ  = NQ_;   // 4194304
    const size_t nWi = NWI_;  // 3145728
    const size_t nWo = NWO_;  // 1048576

    bf16* qkv  = (bf16*)d_ws;                         // [4096,3072]; later attn out
    bf16* Qh   = qkv + (size_t)4096 * 3072;
    bf16* Kt   = Qh + nQ;                             // tiled+swizzled K
    bf16* qbf  = Kt + nQ;                             // query bf16; later Vt tiles
    bf16* wibf = qbf + nQ;
    bf16* wobf = wibf + nWi;
    int* lengths = (int*)(wobf + nWo);
    bf16* Vt   = qbf;    // alias: qbf dead after gemm1
    bf16* attn = qkv;    // alias: qkv dead after rope/v_transpose

    compute_lengths<<<B_, 256, 0, stream>>>(mask, lengths);
    cvt_all<<<(int)((nQ + nWi + nWo) / (256 * 8)), 256, 0, stream>>>(
        query, W_in, W_out, qbf, cosw);

    dim3 g1(3072 / 128, 4096 / 128);
    gemm_nt<<<g1, 256, 0, stream>>>(qbf, wibf, qkv, 4096, 3072, 1024, 0, cosw);

    rope_split<<<(B_ * S_ * H_ * HD_) / 256, 256, 0, stream>>>(qkv, sin_q, cos_q, Qh, Kt);
    dim3 gv(S_ / 64, H_, B_);
    v_transpose<<<gv, 256, 0, stream>>>(qkv, Vt);

    attn_fused<<<1024, 256, 0, stream>>>(Qh, Kt, Vt, lengths, attn);

    dim3 g2(1024 / 128, 4096 / 128);
    gemm_nt<<<g2, 256, 0, stream>>>(attn, wobf, d_out, 4096, 1024, 1024, 1, cosw);
}

// Round 9
// 193.262 us; speedup vs baseline: 1.8692x; 1.0699x over previous
//
#include <hip/hip_runtime.h>
#include <hip/hip_bf16.h>

// Problem constants
#define B_ 2
#define S_ 2048
#define DM_ 1024
#define TD_ 1024
#define H_ 16
#define HD_ 64

using bf16 = __hip_bfloat16;
typedef __attribute__((ext_vector_type(8))) short s8v;   // 8 bf16 = one MFMA A/B frag
typedef __attribute__((ext_vector_type(4))) float f4v;   // MFMA C/D frag

__device__ __forceinline__ f4v mfma_bf16(s8v a, s8v b, f4v c) {
    return __builtin_amdgcn_mfma_f32_16x16x32_bf16(a, b, c, 0, 0, 0);
}

// HW packed fp32x2 -> bf16x2 (RNE), single VOP3 instr on CDNA3/4
__device__ __forceinline__ unsigned cvt_pk_bf16(float a, float b) {
    unsigned r;
    asm("v_cvt_pk_bf16_f32 %0, %1, %2" : "=v"(r) : "v"(a), "v"(b));
    return r;
}
__device__ __forceinline__ int2 pack4bf(float a, float b, float c, float d) {
    int2 r;
    r.x = (int)cvt_pk_bf16(a, b);
    r.y = (int)cvt_pk_bf16(c, d);
    return r;
}

// cos_q[0] == 1.0 exactly: fp32 word = 0x3F800000 (low16==0); bf16 pair != 0 low16.
__device__ __forceinline__ bool detect_f32(const unsigned int* __restrict__ cosw) {
    return (cosw[0] & 0xFFFFu) == 0u;
}

__device__ __forceinline__ float ld_f(const void* p, int idx, bool f32) {
    return f32 ? ((const float*)p)[idx]
               : __bfloat162float(((const bf16*)p)[idx]);
}

// async global -> LDS, 16 B per lane (HW: dst = wave-uniform base + lane*16)
__device__ __forceinline__ void gload_lds16(const bf16* g, void* l) {
    __builtin_amdgcn_global_load_lds(
        (const __attribute__((address_space(1))) unsigned int*)(const void*)g,
        (__attribute__((address_space(3))) unsigned int*)l,
        16, 0, 0);
}

#define NQ_  (B_ * S_ * DM_)
#define NWI_ (3 * TD_ * DM_)
#define NWO_ (DM_ * TD_)
#define NCVT_BLOCKS ((NQ_ + NWI_ + NWO_) / 2048)   // 4096

// ---------------------------------------------------------------------------
// Fused prep: blocks [0,4096) convert (query|W_in|W_out) -> bf16;
// blocks 4096..4097 compute lengths[b] from the mask (4-way storage detect).
// ---------------------------------------------------------------------------
__global__ __launch_bounds__(256)
void prep_all(const void* __restrict__ q, const void* __restrict__ wi,
              const void* __restrict__ wo, bf16* __restrict__ dst,
              const void* __restrict__ mask, int* __restrict__ lengths,
              const unsigned int* __restrict__ cosw) {
    const int bid = blockIdx.x;
    if (bid < NCVT_BLOCKS) {
        const bool f32 = detect_f32(cosw);
        int i = (bid * 256 + threadIdx.x) * 8;
        const void* src; int off;
        if (i < NQ_)              { src = q;  off = i; }
        else if (i < NQ_ + NWI_)  { src = wi; off = i - NQ_; }
        else                      { src = wo; off = i - NQ_ - NWI_; }
        if (f32) {
            const float* p = (const float*)src + off;
            float4 x = *reinterpret_cast<const float4*>(p);
            float4 y = *reinterpret_cast<const float4*>(p + 4);
            union { unsigned u[4]; int4 v; } t;
            t.u[0] = cvt_pk_bf16(x.x, x.y);
            t.u[1] = cvt_pk_bf16(x.z, x.w);
            t.u[2] = cvt_pk_bf16(y.x, y.y);
            t.u[3] = cvt_pk_bf16(y.z, y.w);
            *reinterpret_cast<int4*>(dst + i) = t.v;
        } else {
            *reinterpret_cast<int4*>(dst + i) =
                *reinterpret_cast<const int4*>((const bf16*)src + off);
        }
        return;
    }
    // lengths path
    int b = bid - NCVT_BLOCKS;
    unsigned int w0 = ((const unsigned int*)mask)[0];
    int enc;                 // 0=i32, 1=u8, 2=bf16, 3=f32
    if (w0 == 1u) enc = 0;
    else if (w0 == 0x01010101u) enc = 1;
    else if (w0 == 0x3F803F80u) enc = 2;
    else enc = 3;
    int cnt = 0;
    for (int s = threadIdx.x; s < S_; s += 256) {
        int i = b * S_ + s;
        bool v;
        if (enc == 0)      v = ((const int*)mask)[i] != 0;
        else if (enc == 1) v = ((const unsigned char*)mask)[i] != 0;
        else if (enc == 2) v = ((const unsigned short*)mask)[i] != 0;
        else               v = ((const float*)mask)[i] != 0.f;
        cnt += v ? 1 : 0;
    }
    __shared__ int red[256];
    red[threadIdx.x] = cnt;
    __syncthreads();
    for (int off = 128; off > 0; off >>= 1) {
        if (threadIdx.x < off) red[threadIdx.x] += red[threadIdx.x + off];
        __syncthreads();
    }
    if (threadIdx.x == 0) lengths[b] = red[0];
}

// ---------------------------------------------------------------------------
// NT GEMM: C[M][N] = A[M][K]*Bm[N][K]^T. bf16 in, fp32 acc. BK=64,
// global_load_lds width-16, XOR-swizzled LDS. MFMA operands SWAPPED
// (D = Bm_tile * A_tile) so each lane owns 4 consecutive n -> b64/b128 stores.
// c_dyn: 1 -> write detected dtype (fp32 if inputs fp32), 0 -> bf16.
// ---------------------------------------------------------------------------
__global__ __launch_bounds__(256)
void gemm_nt(const bf16* __restrict__ A, const bf16* __restrict__ Bm,
             void* __restrict__ C, int M, int N, int K,
             int c_dyn, const unsigned int* __restrict__ cosw) {
    __shared__ bf16 lds_a[128 * 64];   // 16 KB, [row][chunk^(row&7)]
    __shared__ bf16 lds_b[128 * 64];

    const bool cf32 = c_dyn && detect_f32(cosw);

    const int t = threadIdx.x;
    const int wave = t >> 6, lane = t & 63;
    const int quad = lane >> 4, l16 = lane & 15;
    const int wm = wave >> 1, wn = wave & 1;
    const int m0 = blockIdx.y * 128, n0 = blockIdx.x * 128;
    const int wuni = __builtin_amdgcn_readfirstlane(wave);   // wave-uniform

    f4v acc[4][4];
    #pragma unroll
    for (int i = 0; i < 4; i++)
        #pragma unroll
        for (int j = 0; j < 4; j++)
            acc[i][j] = f4v{0.f, 0.f, 0.f, 0.f};

    for (int k0 = 0; k0 < K; k0 += 64) {
        __syncthreads();                 // prior reads done before restage
        #pragma unroll
        for (int i = 0; i < 4; i++) {
            int ci = i * 256 + t;        // chunk 0..1023 (16B each)
            int row = ci >> 3;
            int csrc = (ci & 7) ^ (row & 7);
            gload_lds16(A + (size_t)(m0 + row) * K + k0 + csrc * 8,
                        (char*)lds_a + i * 4096 + wuni * 1024);
            gload_lds16(Bm + (size_t)(n0 + row) * K + k0 + csrc * 8,
                        (char*)lds_b + i * 4096 + wuni * 1024);
        }
        __syncthreads();                 // drains vmcnt -> staged data visible

        #pragma unroll
        for (int kk = 0; kk < 2; kk++) {
            s8v afr[4], bfr[4];
            #pragma unroll
            for (int mb = 0; mb < 4; mb++) {
                int r = wm * 64 + mb * 16 + l16;
                int ch = (kk * 4 + quad) ^ (l16 & 7);
                afr[mb] = *reinterpret_cast<const s8v*>(&lds_a[r * 64 + ch * 8]);
            }
            #pragma unroll
            for (int nb = 0; nb < 4; nb++) {
                int r = wn * 64 + nb * 16 + l16;
                int ch = (kk * 4 + quad) ^ (l16 & 7);
                bfr[nb] = *reinterpret_cast<const s8v*>(&lds_b[r * 64 + ch * 8]);
            }
            // swapped: D[i=n-in-16][j=m-in-16], lane j=l16, regs i=quad*4+rr
            #pragma unroll
            for (int mb = 0; mb < 4; mb++)
                #pragma unroll
                for (int nb = 0; nb < 4; nb++)
                    acc[mb][nb] = mfma_bf16(bfr[nb], afr[mb], acc[mb][nb]);
        }
    }

    // epilogue: m = m0+wm*64+mb*16+l16 (per lane), n = n0+wn*64+nb*16+quad*4+rr
    #pragma unroll
    for (int mb = 0; mb < 4; mb++) {
        int m = m0 + wm * 64 + mb * 16 + l16;
        #pragma unroll
        for (int nb = 0; nb < 4; nb++) {
            int n = n0 + wn * 64 + nb * 16 + quad * 4;
            f4v v = acc[mb][nb];
            if (cf32) {
                *reinterpret_cast<f4v*>(&((float*)C)[(size_t)m * N + n]) = v;
            } else {
                *reinterpret_cast<int2*>(&((bf16*)C)[(size_t)m * N + n]) =
                    pack4bf(v[0], v[1], v[2], v[3]);
            }
        }
    }
}

// ---------------------------------------------------------------------------
// Fused RoPE + V-transpose.
// Blocks [0,16384): RoPE. Q -> Qh [B,H,S,64] linear, pre-scaled 0.125*log2e
// (softmax uses exp2). K -> Kt tiled+swizzled (tile (b,h,sb), slot
// (s&63, c^(s&7)) holds chunk c).
// Blocks [16384,17408): V transpose -> Vt tiled+swizzled [d][keychunk^(d&7)].
// ---------------------------------------------------------------------------
__global__ __launch_bounds__(256)
void rope_vt(const bf16* __restrict__ qkv,
             const void* __restrict__ sin_t, const void* __restrict__ cos_t,
             bf16* __restrict__ Qh, bf16* __restrict__ Kt, bf16* __restrict__ Vt) {
    __shared__ bf16 tile[64 * 72];     // used by vt path only
    const int bid = blockIdx.x;
    if (bid < 16384) {
        const bool f32 = detect_f32((const unsigned int*)cos_t);
        int idx = bid * 256 + threadIdx.x;   // B*S*H*HD = 2^22
        int d = idx & 63;
        int h = (idx >> 6) & 15;
        int s = (idx >> 10) & 2047;
        int b = idx >> 21;
        size_t row = (size_t)(b * S_ + s) * 3072;
        int col  = h * 64 + d;
        int colp = h * 64 + ((d + 32) & 63);
        float sgn = (d < 32) ? -1.f : 1.f;
        float cs = ld_f(cos_t, s * 64 + d, f32);
        float sn = ld_f(sin_t, s * 64 + d, f32);
        float q  = __bfloat162float(qkv[row + col]);
        float qp = __bfloat162float(qkv[row + colp]);
        float k  = __bfloat162float(qkv[row + 1024 + col]);
        float kp = __bfloat162float(qkv[row + 1024 + colp]);
        Qh[((size_t)((b * H_ + h) * S_ + s)) * 64 + d] =
            __float2bfloat16((q * cs + sgn * qp * sn) * 0.180336880f);  // 1/8*log2e
        size_t ktile = ((size_t)(b * H_ + h) * 32 + (s >> 6)) * 4096;
        int dp = ((((d >> 3) ^ (s & 7)) << 3) | (d & 7));
        Kt[ktile + (s & 63) * 64 + dp] = __float2bfloat16(k * cs + sgn * kp * sn);
        return;
    }
    // V-transpose path
    const int vid = bid - 16384;       // 0..1023
    const int sb = vid & 31, h = (vid >> 5) & 15, b = vid >> 9;
    const int t = threadIdx.x;
    #pragma unroll
    for (int i = 0; i < 2; i++) {
        int id = i * 256 + t;          // 0..511
        int row = id >> 3, c = id & 7;
        *reinterpret_cast<int4*>(&tile[row * 72 + c * 8]) =
            *reinterpret_cast<const int4*>(
                qkv + (size_t)(b * S_ + sb * 64 + row) * 3072 + 2048 + h * 64 + c * 8);
    }
    __syncthreads();
    const size_t tb = ((size_t)(b * H_ + h) * 32 + sb) * 4096;
    #pragma unroll
    for (int i = 0; i < 2; i++) {
        int id = i * 256 + t;
        int d = id >> 3, kc = id & 7;  // kc = 8-key chunk
        union { short s[8]; int4 v; } u;
        #pragma unroll
        for (int e = 0; e < 8; e++)
            u.s[e] = reinterpret_cast<const short*>(tile)[(kc * 8 + e) * 72 + d];
        *reinterpret_cast<int4*>(Vt + tb + d * 64 + ((kc ^ (d & 7)) * 8)) = u.v;
    }
}

// ---------------------------------------------------------------------------
// Flash attention v6: transposed-S + depth-2 pipeline + CAUSAL PAIRING.
// 512 blocks; block handles qb = p (pass 0) and 31-p (pass 1): uniform 33
// tile-iters per block, exactly 2 blocks/CU, no scheduler churn/tail.
// XCD-clustered: bid&7 = XCD, all blocks of a (b,h) on one XCD (2 MB <= L2).
// Per iter: stage V[kt]+K[kt+1]; S-MFMA[kt]; exp/pack/PV[kt-1]; 1 barrier.
// ---------------------------------------------------------------------------
__global__ __launch_bounds__(256)
void attn_fused(const bf16* __restrict__ Qh, const bf16* __restrict__ Kt,
                const bf16* __restrict__ Vt, const int* __restrict__ lengths,
                bf16* __restrict__ out) {
    __shared__ bf16 k_buf[2 * 4096];   // K tiles  [row(key)][chunk^(key&7)]
    __shared__ bf16 v_buf[2 * 4096];   // Vt tiles [row(d)][keychunk^(d&7)]
    __shared__ bf16 lds_p[4 * 16 * 72];// per-wave P tile [qrow][key]

    const int t = threadIdx.x, wave = t >> 6, lane = t & 63;
    const int quad = lane >> 4, l16 = lane & 15;
    // XCD-clustered decode: 512 blocks, 64 slots/XCD = 4 bh x 16 pairs
    const int bid = blockIdx.x;
    const int slot = bid >> 3;                    // 0..63
    const int bh = (bid & 7) * 4 + (slot >> 4);   // all of a bh on one XCD
    const int p = slot & 15;                      // pair index
    const int b = bh >> 4, h = bh & 15;

    const size_t hb = (size_t)bh * S_ * 64;          // Qh base
    const bf16* Ktp = Kt + (size_t)bh * 32 * 4096;   // tile array base
    const bf16* Vtp = Vt + (size_t)bh * 32 * 4096;
    const int wuni = __builtin_amdgcn_readfirstlane(wave);
    int len_raw = lengths[b];
    const int len_b = len_raw < 1 ? 1 : (len_raw > S_ ? S_ : len_raw);
    const int nkt_len = (len_b + 63) >> 6;

    #pragma unroll
    for (int pass = 0; pass < 2; pass++) {
        const int qb = pass ? (31 - p) : p;
        const int qbase = qb * 64;
        const int qrow_g = qbase + wave * 16 + l16;   // this lane's q-row
        const int kmax = (qrow_g < len_b - 1) ? qrow_g : (len_b - 1);

        s8v qf[2];
        {
            const bf16* qptr = Qh + hb + (size_t)qrow_g * 64 + quad * 8;
            qf[0] = *reinterpret_cast<const s8v*>(qptr);
            qf[1] = *reinterpret_cast<const s8v*>(qptr + 32);
        }

        f4v o_acc[4];
        #pragma unroll
        for (int a = 0; a < 4; a++) o_acc[a] = f4v{0.f, 0.f, 0.f, 0.f};
        float l_sum = 0.f;

        const int nkt = (qb + 1) < nkt_len ? (qb + 1) : nkt_len;

        f4v s_prev[4];
        auto process_tile = [&](int pt, const bf16* vb) {
            const int pbase = pt * 64;
            const bool tail = (pt == qb) || (pbase + 64 > len_b);  // uniform
            #pragma unroll
            for (int a = 0; a < 4; a++) {
                float e0[4];
                #pragma unroll
                for (int r = 0; r < 4; r++) {
                    float e = __builtin_amdgcn_exp2f(s_prev[a][r]);
                    if (tail) {
                        int key = pbase + a * 16 + quad * 4 + r;
                        e = (key <= kmax) ? e : 0.f;
                    }
                    e0[r] = e;
                    l_sum += e;
                }
                *reinterpret_cast<int2*>(
                    &lds_p[(wave * 16 + l16) * 72 + a * 16 + quad * 4]) =
                    pack4bf(e0[0], e0[1], e0[2], e0[3]);
            }
            // wave-local: P writes -> P reads (lds_p region is per-wave)
            asm volatile("s_waitcnt lgkmcnt(0)" ::: "memory");
            #pragma unroll
            for (int kk = 0; kk < 2; kk++) {
                s8v pf = *reinterpret_cast<const s8v*>(
                    &lds_p[(wave * 16 + l16) * 72 + kk * 32 + quad * 8]);
                #pragma unroll
                for (int a = 0; a < 4; a++) {
                    int ch = (kk * 4 + quad) ^ (l16 & 7);
                    s8v vf = *reinterpret_cast<const s8v*>(
                        &vb[(a * 16 + l16) * 64 + ch * 8]);
                    o_acc[a] = mfma_bf16(vf, pf, o_acc[a]);
                }
            }
        };

        // prologue: stage K[0] (pass-0 drain reads only v_buf/lds_p; no race)
        #pragma unroll
        for (int i = 0; i < 2; i++) {
            int ci = i * 256 + t;
            gload_lds16(Ktp + ci * 8, (char*)k_buf + i * 4096 + wuni * 1024);
        }
        __syncthreads();   // K[0] resident (drains vmcnt)

        for (int kt = 0; kt < nkt; kt++) {
            const int cur = kt & 1;
            // stage V[kt] -> vbuf[cur] (one tile behind K)
            {
                const bf16* vst = Vtp + (size_t)kt * 4096;
                #pragma unroll
                for (int i = 0; i < 2; i++) {
                    int ci = i * 256 + t;
                    gload_lds16(vst + ci * 8,
                                (char*)v_buf + cur * 8192 + i * 4096 + wuni * 1024);
                }
            }
            // stage K[kt+1] -> kbuf[cur^1]
            if (kt + 1 < nkt) {
                const bf16* kst = Ktp + (size_t)(kt + 1) * 4096;
                #pragma unroll
                for (int i = 0; i < 2; i++) {
                    int ci = i * 256 + t;
                    gload_lds16(kst + ci * 8,
                                (char*)k_buf + (cur ^ 1) * 8192 + i * 4096 + wuni * 1024);
                }
            }

            // S^T[kt] = K Q^T : lane holds (key = a*16+quad*4+r, qrow = l16)
            const bf16* kb = k_buf + cur * 4096;
            f4v s_acc[4];
            #pragma unroll
            for (int a = 0; a < 4; a++) s_acc[a] = f4v{0.f, 0.f, 0.f, 0.f};
            #pragma unroll
            for (int kk = 0; kk < 2; kk++) {
                #pragma unroll
                for (int a = 0; a < 4; a++) {
                    int ch = (kk * 4 + quad) ^ (l16 & 7);
                    s8v kf = *reinterpret_cast<const s8v*>(
                        &kb[(a * 16 + l16) * 64 + ch * 8]);
                    s_acc[a] = mfma_bf16(kf, qf[kk], s_acc[a]);
                }
            }

            // overlap: previous tile's exp/pack/PV under this tile's S-MFMA
            if (kt > 0) process_tile(kt - 1, v_buf + ((kt - 1) & 1) * 4096);

            #pragma unroll
            for (int a = 0; a < 4; a++) s_prev[a] = s_acc[a];

            __syncthreads();   // V[kt], K[kt+1] staged; LDS reads done before reuse
        }
        // drain: last tile
        process_tile(nkt - 1, v_buf + ((nkt - 1) & 1) * 4096);

        // reduce l across the 4 quads sharing this q-row, then b64 epilogue
        l_sum += __shfl_xor(l_sum, 16);
        l_sum += __shfl_xor(l_sum, 32);
        float inv_l = 1.f / l_sum;
        size_t orow = ((size_t)(b * S_ + qrow_g)) * TD_ + h * 64;
        #pragma unroll
        for (int a = 0; a < 4; a++) {
            *reinterpret_cast<int2*>(&out[orow + a * 16 + quad * 4]) =
                pack4bf(o_acc[a][0] * inv_l, o_acc[a][1] * inv_l,
                        o_acc[a][2] * inv_l, o_acc[a][3] * inv_l);
        }
    }
}

// ---------------------------------------------------------------------------
extern "C" void kernel_launch(void* const* d_in, const int* in_sizes, int n_in,
                              void* d_out, int out_size, void* d_ws, size_t ws_size,
                              hipStream_t stream) {
    const void* query = d_in[0];   // [B,S,DM]  fp32 (auto-detected, bf16-safe)
    const void* W_in  = d_in[1];   // [3TD,DM]
    const void* W_out = d_in[2];   // [DM,TD]
    const void* sin_q = d_in[3];   // [S,HD]
    const void* cos_q = d_in[4];   // [S,HD]   dtype probe
    const void* mask  = d_in[5];   // [B,S] bool, storage auto-detected
    const unsigned int* cosw = (const unsigned int*)cos_q;

    const size_t nQ  = NQ_;   // 4194304
    const size_t nWi = NWI_;  // 3145728
    const size_t nWo = NWO_;  // 1048576

    bf16* qkv  = (bf16*)d_ws;                         // [4096,3072]; later attn out
    bf16* Qh   = qkv + (size_t)4096 * 3072;
    bf16* Kt   = Qh + nQ;                             // tiled+swizzled K
    bf16* qbf  = Kt + nQ;                             // query bf16; later Vt tiles
    bf16* wibf = qbf + nQ;
    bf16* wobf = wibf + nWi;
    int* lengths = (int*)(wobf + nWo);
    bf16* Vt   = qbf;    // alias: qbf dead after gemm1
    bf16* attn = qkv;    // alias: qkv dead after rope_vt

    prep_all<<<NCVT_BLOCKS + B_, 256, 0, stream>>>(
        query, W_in, W_out, qbf, mask, lengths, cosw);

    dim3 g1(3072 / 128, 4096 / 128);
    gemm_nt<<<g1, 256, 0, stream>>>(qbf, wibf, qkv, 4096, 3072, 1024, 0, cosw);

    rope_vt<<<16384 + 1024, 256, 0, stream>>>(qkv, sin_q, cos_q, Qh, Kt, Vt);

    attn_fused<<<512, 256, 0, stream>>>(Qh, Kt, Vt, lengths, attn);

    dim3 g2(1024 / 128, 4096 / 128);
    gemm_nt<<<g2, 256, 0, stream>>>(attn, wobf, d_out, 4096, 1024, 1024, 1, cosw);
}